// Round 10
// baseline (998.283 us; speedup 1.0000x reference)
//
#include <hip/hip_runtime.h>
#include <math.h>

typedef __fp16 f16;
typedef __fp16 f16x8 __attribute__((ext_vector_type(8)));
typedef __fp16 f16x4 __attribute__((ext_vector_type(4)));
typedef float  f32x4 __attribute__((ext_vector_type(4)));

#define T_SEQ 2048
#define HID   2048
#define NQH   16
#define NKV   4
#define HD    128
#define FFN_D 4096
#define NEXP  8

// async global->LDS DMA, 16B per lane; LDS dest is wave-uniform base (+lane*16 in HW)
#define GLDS(gp, lp) __builtin_amdgcn_global_load_lds( \
    (const __attribute__((address_space(1))) void*)(gp), \
    (__attribute__((address_space(3))) void*)(lp), 16, 0, 0)

__device__ __forceinline__ float wredsum(float v){
#pragma unroll
  for (int m = 32; m; m >>= 1) v += __shfl_xor(v, m, 64);
  return v;
}
__device__ __forceinline__ float wredmax(float v){
#pragma unroll
  for (int m = 32; m; m >>= 1) v = fmaxf(v, __shfl_xor(v, m, 64));
  return v;
}

// ---------------------------------------------------------------------------
// 4-wave 128x128 (BK=32) grouped f16 GEMM (m97 geometry + counted prefetch).
// 32 KB LDS, __launch_bounds__(256,4) -> 4 blocks/CU: inter-block TLP hides
// barrier/vmcnt stalls (r9 post-mortem: 256^2 tile = 1 block/CU, 33% MfmaUtil,
// stall-bound). Counted vmcnt(4) 2-deep double-buffer, never drains mid-loop.
// Swizzle: LDS[row][g16] = global[row][g16 ^ ((row>>1)&3)] (bijective, uniform
// banks); read cp = (fq ^ ((fr>>1)&3))*8; inverse on global source (rule #21).
// IDENTITY block mapping (grouped early-exit grids break under fl-swizzle, r6).
// EPI: 0 = f32 store, 3 = f16 store.
// MODE: 0 plain; 1 split-K (z = expert*2 + Khalf, half1 -> Cv2);
//       2 merged two-B (z = expert + 8*sel; sel selects B2/Cv2).
// ---------------------------------------------------------------------------
template<bool GATHER_A, bool SCATTER_C, int EPI, int MODE>
__global__ __launch_bounds__(256, 4)
void gemm8(const f16* __restrict__ A, const f16* __restrict__ B,
           const f16* __restrict__ B2,
           void* __restrict__ Cv, void* __restrict__ Cv2,
           int K, int lda, int ldb, int ldc, long sBz,
           const int* __restrict__ grp_off, const int* __restrict__ a_rows,
           const int* __restrict__ c_rows)
{
  __shared__ __align__(16) f16 Lds[2][8192];   // per buf: A[128][32] @0 | B[128][32] @4096 (f16 units)
  const int bn = blockIdx.x, bm = blockIdx.y, z = blockIdx.z;
  int e = z, half = 0, sel = 0;
  if (MODE == 1) { e = z >> 1; half = z & 1; }
  if (MODE == 2) { e = z & 7;  sel  = z >> 3; }
  const int rowBase  = grp_off[e];
  const int rowCount = grp_off[e + 1] - rowBase;
  if (rowCount <= 0 || bm * 128 >= rowCount) return;
  const f16* Bz = ((MODE == 2 && sel) ? B2 : B) + (long)e * sBz;
  int k0 = 0, kN = K;
  if (MODE == 1) { kN = K >> 1; k0 = half * kN; }
  const int nt = kN >> 5;   // K-tiles of 32

  const int tid = threadIdx.x, lane = tid & 63, w = tid >> 6;
  const int wr = w >> 1, wc = w & 1;

  // staging: per tensor 2 sites x 64 rows; thread t covers row (t>>2), granule t&3,
  // global granule pre-swizzled: (t&3) ^ ((t>>3)&3)   [= g ^ ((row>>1)&3)]
  const int srow = tid >> 2;                     // 0..63 within site
  const int scol = (((tid & 3) ^ ((tid >> 3) & 3)) << 3);  // f16 col within 32
  int aoff[2], boff[2];
#pragma unroll
  for (int i = 0; i < 2; i++) {
    int r = bm * 128 + i * 64 + srow;
    if (r > rowCount - 1) r = rowCount - 1;
    const int ar = GATHER_A ? a_rows[rowBase + r] : (rowBase + r);
    aoff[i] = ar * lda + scol + k0;
    boff[i] = (bn * 128 + i * 64 + srow) * ldb + scol + k0;
  }

#define STG8(buf, kk) do { f16* _l = &Lds[buf][0]; \
  GLDS(A  + aoff[0] + (kk), _l +        w * 512); \
  GLDS(A  + aoff[1] + (kk), _l + 2048 + w * 512); \
  GLDS(Bz + boff[0] + (kk), _l + 4096 + w * 512); \
  GLDS(Bz + boff[1] + (kk), _l + 6144 + w * 512); } while (0)

  const int fr = lane & 15, fq = lane >> 4;
  const int cp = ((fq ^ ((fr >> 1) & 3)) << 3);
  const int aRow = (wr * 64 + fr) * 32;          // + m*512
  const int bRow = 4096 + (wc * 64 + fr) * 32;   // + n*512

  f32x4 acc[4][4] = {};

  STG8(0, 0);
  if (nt > 1) STG8(1, 32);

  for (int kt = 0; kt < nt; kt++) {
    if (kt + 1 < nt) asm volatile("s_waitcnt vmcnt(4)" ::: "memory");
    else             asm volatile("s_waitcnt vmcnt(0)" ::: "memory");
    __builtin_amdgcn_s_barrier();
    const f16* Lb = &Lds[kt & 1][0];
    f16x8 bf[4], af[4];
#pragma unroll
    for (int n = 0; n < 4; n++) bf[n] = *(const f16x8*)(Lb + bRow + n * 512 + cp);
#pragma unroll
    for (int m = 0; m < 4; m++) af[m] = *(const f16x8*)(Lb + aRow + m * 512 + cp);
    asm volatile("s_waitcnt lgkmcnt(0)" ::: "memory");
    __builtin_amdgcn_sched_barrier(0);
    __builtin_amdgcn_s_barrier();                 // all reads of buf done -> safe to restage
    if (kt + 2 < nt) STG8(kt & 1, (kt + 2) * 32);
    __builtin_amdgcn_s_setprio(1);
#pragma unroll
    for (int m = 0; m < 4; m++)
#pragma unroll
      for (int n = 0; n < 4; n++)
        acc[m][n] = __builtin_amdgcn_mfma_f32_16x16x32_f16(af[m], bf[n], acc[m][n], 0, 0, 0);
    __builtin_amdgcn_s_setprio(0);
  }
#undef STG8

  float* Cf = (MODE == 1 && half) ? (float*)Cv2 : (float*)Cv;
  f16*   Ch = (MODE == 2 && sel)  ? (f16*)Cv2   : (f16*)Cv;
  const int ccol0 = bn * 128 + wc * 64 + fr;
#pragma unroll
  for (int m = 0; m < 4; m++) {
#pragma unroll
    for (int r = 0; r < 4; r++) {
      const int g = bm * 128 + wr * 64 + m * 16 + fq * 4 + r;
      if (g >= rowCount) continue;
      const long orow = SCATTER_C ? (long)c_rows[rowBase + g] : (long)(rowBase + g);
#pragma unroll
      for (int n = 0; n < 4; n++) {
        const long idx = orow * ldc + (ccol0 + n * 16);
        if (EPI == 3) Ch[idx] = (f16)acc[m][n][r];
        else          Cf[idx] = acc[m][n][r];
      }
    }
  }
}

// ---------------------------------------------------------------------------
// 8-wave 128x128 (BK=64) fused hi/lo 3-term GEMM, counted 2-deep schedule:
//   C = Ah*Bh^T + Ah*Bl^T + Al*Bh^T   (fp32-faithful)
// IDENTITY block mapping. LDS 2 x 64KB (Ah|Al|Bh|Bl x 128x64).
// EPI: 0 f32, 2 f32+resid. CAUSAL: skip bn>bm.
// PVK: attention PV mode: z = head(0..7) | chunk(0..1)<<3; K causally limited
//      to (bm+1)*128, chunk c covers [c*1024, c*1024+1024); C += chunk*T*HID.
// ---------------------------------------------------------------------------
template<int EPI, int CAUSAL, bool PVK>
__global__ __launch_bounds__(512, 2)
void gemm83(const f16* __restrict__ Ah, const f16* __restrict__ Al,
            const f16* __restrict__ Bh, const f16* __restrict__ Bl,
            void* __restrict__ Cv, int K, int lda, int ldb, int ldc,
            long sAz, long sBz, int bdiv, long sCz,
            const float* __restrict__ resid)
{
  __shared__ __align__(16) f16 Lds[2][32768];  // Ah 0 | Al 8192 | Bh 16384 | Bl 24576
  const int bn = blockIdx.x, bm = blockIdx.y, z = blockIdx.z;
  if (CAUSAL == 1 && bn > bm) return;
  int head = z, chunk = 0;
  if (PVK) { head = z & 7; chunk = z >> 3; }
  int kstart = 0, kend = K;
  if (PVK) {
    const int km = (bm + 1) * 128;
    if (km < kend) kend = km;
    kstart = chunk * 1024;
    if (kstart >= kend) return;
    if (kend > kstart + 1024) kend = kstart + 1024;
  }
  const int nt = (kend - kstart) >> 6;

  const f16* Ahz = Ah + (long)head * sAz;
  const f16* Alz = Al + (long)head * sAz;
  const long zb = (long)(bdiv ? head / bdiv : head) * sBz;
  const f16* Bhz = Bh + zb;
  const f16* Blz = Bl + zb;

  const int tid = threadIdx.x, lane = tid & 63, w = tid >> 6;
  const int wr = w >> 2, wc = w & 3;

  const int srow = w * 8 + (lane >> 3);
  const int scol = (((lane & 7) ^ (lane >> 3)) << 3);
  long ar[2], br[2];
#pragma unroll
  for (int i = 0; i < 2; i++) {
    ar[i] = (long)(bm * 128 + i * 64 + srow) * lda + scol + kstart;
    br[i] = (long)(bn * 128 + i * 64 + srow) * ldb + scol + kstart;
  }

#define STG83(buf, kk) do { f16* _l = &Lds[buf][0]; \
  GLDS(Ahz + ar[0] + (kk), _l +         w * 512); GLDS(Ahz + ar[1] + (kk), _l +  4096 + w * 512); \
  GLDS(Alz + ar[0] + (kk), _l +  8192 + w * 512); GLDS(Alz + ar[1] + (kk), _l + 12288 + w * 512); \
  GLDS(Bhz + br[0] + (kk), _l + 16384 + w * 512); GLDS(Bhz + br[1] + (kk), _l + 20480 + w * 512); \
  GLDS(Blz + br[0] + (kk), _l + 24576 + w * 512); GLDS(Blz + br[1] + (kk), _l + 28672 + w * 512); } while (0)

  const int fr = lane & 15, fq = lane >> 4;
  const int cp0 = ((fq       ^ (fr & 7)) << 3);
  const int cp1 = (((4 | fq) ^ (fr & 7)) << 3);
  const int aRow = (wr * 64 + fr) * 64;           // + m*1024 ; Al at +8192
  const int bRow = 16384 + (wc * 32 + fr) * 64;   // + n*1024 ; Bl at +8192

  f32x4 acc[4][2] = {};

  STG83(0, 0);
  if (nt > 1) STG83(1, 64);

  for (int kt = 0; kt < nt; kt++) {
    if (kt + 1 < nt) asm volatile("s_waitcnt vmcnt(8)" ::: "memory");
    else             asm volatile("s_waitcnt vmcnt(0)" ::: "memory");
    __builtin_amdgcn_s_barrier();
    const f16* Lb = &Lds[kt & 1][0];
#pragma unroll
    for (int ks = 0; ks < 2; ks++) {
      const int cp = ks ? cp1 : cp0;
      f16x8 ah[4], al[4], bh[2], bl[2];
#pragma unroll
      for (int n = 0; n < 2; n++) {
        bh[n] = *(const f16x8*)(Lb + bRow +        n * 1024 + cp);
        bl[n] = *(const f16x8*)(Lb + bRow + 8192 + n * 1024 + cp);
      }
#pragma unroll
      for (int m = 0; m < 4; m++) {
        ah[m] = *(const f16x8*)(Lb + aRow +        m * 1024 + cp);
        al[m] = *(const f16x8*)(Lb + aRow + 8192 + m * 1024 + cp);
      }
      __builtin_amdgcn_s_setprio(1);
#pragma unroll
      for (int m = 0; m < 4; m++)
#pragma unroll
        for (int n = 0; n < 2; n++) {
          acc[m][n] = __builtin_amdgcn_mfma_f32_16x16x32_f16(ah[m], bh[n], acc[m][n], 0, 0, 0);
          acc[m][n] = __builtin_amdgcn_mfma_f32_16x16x32_f16(ah[m], bl[n], acc[m][n], 0, 0, 0);
          acc[m][n] = __builtin_amdgcn_mfma_f32_16x16x32_f16(al[m], bh[n], acc[m][n], 0, 0, 0);
        }
      __builtin_amdgcn_s_setprio(0);
    }
    __builtin_amdgcn_s_barrier();
    if (kt + 2 < nt) STG83(kt & 1, (kt + 2) * 64);
  }
#undef STG83

  float* Cf = (float*)Cv + (long)head * sCz + (PVK ? (long)chunk * T_SEQ * HID : 0);
  const int crow0 = bm * 128 + wr * 64 + fq * 4;
  const int ccol0 = bn * 128 + wc * 32 + fr;
#pragma unroll
  for (int m = 0; m < 4; m++) {
#pragma unroll
    for (int r = 0; r < 4; r++) {
      const long row = crow0 + m * 16 + r;
#pragma unroll
      for (int n = 0; n < 2; n++) {
        const long idx = row * ldc + (ccol0 + n * 16);
        const float v = acc[m][n][r];
        if (EPI == 2) Cf[idx] = v + resid[idx];
        else          Cf[idx] = v;
      }
    }
  }
}

// ---------------------------------------------------------------------------
template<bool SPLIT>
__global__ __launch_bounds__(256)
void rmsnorm_k(const float* __restrict__ x, const float* __restrict__ w,
               f16* __restrict__ hi, f16* __restrict__ lo, float* __restrict__ invr_out)
{
  const int t = blockIdx.x, tid = threadIdx.x;
  const float4* xr = (const float4*)(x + (long)t * HID);
  const float4 a = xr[tid * 2], b = xr[tid * 2 + 1];
  float ss = a.x*a.x + a.y*a.y + a.z*a.z + a.w*a.w
           + b.x*b.x + b.y*b.y + b.z*b.z + b.w*b.w;
  ss = wredsum(ss);
  __shared__ float red[4];
  if ((tid & 63) == 0) red[tid >> 6] = ss;
  __syncthreads();
  const float tot  = red[0] + red[1] + red[2] + red[3];
  const float invr = 1.0f / sqrtf(tot * (1.0f / HID) + 1e-5f);
  if (invr_out && tid == 0) invr_out[t] = invr;
  const float4* wr4 = (const float4*)w;
  const float4 wa = wr4[tid * 2], wb = wr4[tid * 2 + 1];
  const float vals[8] = { a.x*wa.x, a.y*wa.y, a.z*wa.z, a.w*wa.w,
                          b.x*wb.x, b.y*wb.y, b.z*wb.z, b.w*wb.w };
  f16x8 hv, lv;
#pragma unroll
  for (int j = 0; j < 8; j++) {
    const float y = vals[j] * invr;
    const f16 h = (f16)y;
    hv[j] = h;
    if (SPLIT) lv[j] = (f16)(y - (float)h);
  }
  const long base = (long)t * HID + tid * 8;
  *(f16x8*)(hi + base) = hv;
  if (SPLIT) *(f16x8*)(lo + base) = lv;
}

// RoPE + hi/lo split; q -> (h,T,128), k -> (g,T,128), v -> transposed (g,128,T)
// inv_freq via per-block LDS table (identical f32 bits to per-thread pow).
__global__ __launch_bounds__(256)
void rope_split_k(const float* __restrict__ qkv, const int* __restrict__ pos,
                  f16* __restrict__ qh, f16* __restrict__ ql,
                  f16* __restrict__ kh, f16* __restrict__ kl,
                  f16* __restrict__ vh, f16* __restrict__ vl)
{
  const int t = blockIdx.x, tid = threadIdx.x;
  __shared__ float invf[64];
  if (tid < 64) {
    const float y = (float)tid * (1.0f / 64.0f);
    invf[tid] = 1.0f / (float)pow(10000.0, (double)y);   // f32-rounded exact pow
  }
  __syncthreads();
  const float p = (float)pos[t];
  const float* row = qkv + (long)t * 3072;

#pragma unroll
  for (int i = 0; i < 4; i++) {
    const int pi = tid + i * 256;
    const int h = pi >> 6, d = pi & 63;
    const float ang = p * invf[d];
    float s, c; sincosf(ang, &s, &c);
    const float x1 = row[h * 128 + d], x2 = row[h * 128 + 64 + d];
    const float o1 = x1 * c - x2 * s;
    const float o2 = x2 * c + x1 * s;
    const long base = ((long)h * T_SEQ + t) * HD;
    { const f16 hh = (f16)o1; qh[base + d]      = hh; ql[base + d]      = (f16)(o1 - (float)hh); }
    { const f16 hh = (f16)o2; qh[base + 64 + d] = hh; ql[base + 64 + d] = (f16)(o2 - (float)hh); }
  }
  {
    const int g = tid >> 6, d = tid & 63;
    const float ang = p * invf[d];
    float s, c; sincosf(ang, &s, &c);
    const float x1 = row[2048 + g * 128 + d], x2 = row[2048 + g * 128 + 64 + d];
    const float o1 = x1 * c - x2 * s;
    const float o2 = x2 * c + x1 * s;
    const long base = ((long)g * T_SEQ + t) * HD;
    { const f16 hh = (f16)o1; kh[base + d]      = hh; kl[base + d]      = (f16)(o1 - (float)hh); }
    { const f16 hh = (f16)o2; kh[base + 64 + d] = hh; kl[base + 64 + d] = (f16)(o2 - (float)hh); }
  }
#pragma unroll
  for (int i = 0; i < 2; i++) {
    const int e = tid + i * 256;
    const int g = e >> 7, d = e & 127;
    const float v = row[2560 + e];
    const long idx = ((long)g * HD + d) * T_SEQ + t;
    const f16 h = (f16)v; vh[idx] = h; vl[idx] = (f16)(v - (float)h);
  }
}

// Row softmax over f32 scores, causal mask, pack P as [hi f16 x 2048 | lo f16 x 2048]
// in place. Causal-bounded: row t touches only segments < (t>>8)+1.
__global__ __launch_bounds__(256)
void softmax_pack(float* __restrict__ S)
{
  const int row  = blockIdx.x * 4 + (threadIdx.x >> 6);
  const int lane = threadIdx.x & 63;
  const int t    = row & (T_SEQ - 1);
  const int nseg = (t >> 8) + 1;
  float* Sr = S + (long)row * T_SEQ;
  float4 v[8];
  const float4* Sr4 = (const float4*)Sr;
#pragma unroll
  for (int i = 0; i < 8; i++) if (i < nseg) v[i] = Sr4[i * 64 + lane];
  const float scale = 0.08838834764831843f; // 128^-0.5
  float vmax = -3.4e38f;
#pragma unroll
  for (int i = 0; i < 8; i++) {
    if (i >= nseg) continue;
    float* pv = (float*)&v[i];
    const int s0 = (i * 64 + lane) * 4;
#pragma unroll
    for (int j = 0; j < 4; j++) {
      const float xx = (s0 + j <= t) ? pv[j] * scale : -3.4e38f;
      pv[j] = xx;
      vmax = fmaxf(vmax, xx);
    }
  }
  vmax = wredmax(vmax);
  float sum = 0.f;
#pragma unroll
  for (int i = 0; i < 8; i++) {
    if (i >= nseg) continue;
    float* pv = (float*)&v[i];
#pragma unroll
    for (int j = 0; j < 4; j++) {
      const float e = (pv[j] > -3.0e38f) ? __expf(pv[j] - vmax) : 0.f;
      pv[j] = e; sum += e;
    }
  }
  sum = wredsum(sum);
  const float rinv = 1.0f / sum;
  __syncthreads();
  f16* P = (f16*)Sr;
#pragma unroll
  for (int i = 0; i < 8; i++) {
    if (i >= nseg) continue;
    const int s0 = (i * 64 + lane) * 4;
    float* pv = (float*)&v[i];
    f16x4 hv, lv;
#pragma unroll
    for (int j = 0; j < 4; j++) {
      const float pr = pv[j] * rinv;
      const f16 ph = (f16)pr;
      hv[j] = ph; lv[j] = (f16)(pr - (float)ph);
    }
    *(f16x4*)(P + s0)         = hv;
    *(f16x4*)(P + T_SEQ + s0) = lv;
  }
}

// Gate: f32 logits from f32 h2 (re-normalized), top-2 + renormalized weights.
__global__ __launch_bounds__(256)
void gate_topk(const float* __restrict__ h2, const float* __restrict__ invr,
               const float* __restrict__ n2w, const float* __restrict__ gw,
               int* __restrict__ top_idx, float* __restrict__ top_w)
{
  const int t = blockIdx.x, tid = threadIdx.x;
  const float r = invr[t];
  const float4* xr = (const float4*)(h2 + (long)t * HID);
  const float4 a = xr[tid * 2], b = xr[tid * 2 + 1];
  const float4* wr4 = (const float4*)n2w;
  const float4 wa = wr4[tid * 2], wb = wr4[tid * 2 + 1];
  const float hn[8] = { a.x*wa.x*r, a.y*wa.y*r, a.z*wa.z*r, a.w*wa.w*r,
                        b.x*wb.x*r, b.y*wb.y*r, b.z*wb.z*r, b.w*wb.w*r };
  float part[8];
#pragma unroll
  for (int e = 0; e < 8; e++) {
    const float4* g4 = (const float4*)(gw + (long)e * HID + tid * 8);
    const float4 ga = g4[0], gb = g4[1];
    part[e] = hn[0]*ga.x + hn[1]*ga.y + hn[2]*ga.z + hn[3]*ga.w
            + hn[4]*gb.x + hn[5]*gb.y + hn[6]*gb.z + hn[7]*gb.w;
  }
#pragma unroll
  for (int e = 0; e < 8; e++) part[e] = wredsum(part[e]);
  __shared__ float red[4][8];
  if ((tid & 63) == 0) {
#pragma unroll
    for (int e = 0; e < 8; e++) red[tid >> 6][e] = part[e];
  }
  __syncthreads();
  if (tid == 0) {
    float lg[8];
#pragma unroll
    for (int e = 0; e < 8; e++) lg[e] = red[0][e] + red[1][e] + red[2][e] + red[3][e];
    int i1 = 0;
    for (int e = 1; e < 8; e++) if (lg[e] > lg[i1]) i1 = e;
    int i2 = -1;
    for (int e = 0; e < 8; e++) { if (e == i1) continue; if (i2 < 0 || lg[e] > lg[i2]) i2 = e; }
    const float q = expf(lg[i2] - lg[i1]);
    top_idx[t * 2] = i1; top_idx[t * 2 + 1] = i2;
    top_w[t * 2]     = 1.0f / (1.0f + q);
    top_w[t * 2 + 1] = q / (1.0f + q);
  }
}

// Single-block routing build: count -> scan -> fill.
__global__ __launch_bounds__(256)
void route_build(const int* __restrict__ ti, int* __restrict__ goff,
                 int* __restrict__ arows, int* __restrict__ crows)
{
  __shared__ int cnt[8], cur[8], off[9];
  const int tid = threadIdx.x;
  if (tid < 8) { cnt[tid] = 0; cur[tid] = 0; }
  __syncthreads();
  for (int i = tid; i < 2 * T_SEQ; i += 256) atomicAdd(&cnt[ti[i]], 1);
  __syncthreads();
  if (tid == 0) {
    int s = 0;
    for (int e = 0; e < NEXP; e++) { off[e] = s; s += cnt[e]; }
    off[NEXP] = s;
    for (int e = 0; e <= NEXP; e++) goff[e] = off[e];
  }
  __syncthreads();
  for (int i = tid; i < 2 * T_SEQ; i += 256) {
    const int e = ti[i];
    const int p = atomicAdd(&cur[e], 1);
    const int slot = off[e] + p;
    arows[slot] = i >> 1;
    crows[slot] = (i & 1) * T_SEQ + (i >> 1);
  }
}

__global__ __launch_bounds__(256)
void silu_mul_k(const f16* __restrict__ h1, const f16* __restrict__ h3, f16* __restrict__ g)
{
  const long i = ((long)blockIdx.x * 256 + threadIdx.x) * 8;
  const f16x8 a = *(const f16x8*)(h1 + i);
  const f16x8 b = *(const f16x8*)(h3 + i);
  f16x8 o;
#pragma unroll
  for (int j = 0; j < 8; j++) {
    const float xx = (float)a[j];
    const float s = xx / (1.0f + __expf(-xx));
    o[j] = (f16)(s * (float)b[j]);
  }
  *(f16x8*)(g + i) = o;
}

__global__ __launch_bounds__(256)
void split_pair_k(const float* __restrict__ src, f16* __restrict__ hi, f16* __restrict__ lo)
{
  const long i = ((long)blockIdx.x * 256 + threadIdx.x) * 8;
  const float4 a = *(const float4*)(src + i);
  const float4 b = *(const float4*)(src + i + 4);
  const float vals[8] = {a.x,a.y,a.z,a.w,b.x,b.y,b.z,b.w};
  f16x8 hv, lv;
#pragma unroll
  for (int j = 0; j < 8; j++) { const f16 h = (f16)vals[j]; hv[j] = h; lv[j] = (f16)(vals[j] - (float)h); }
  *(f16x8*)(hi + i) = hv;
  *(f16x8*)(lo + i) = lv;
}

// attn = chunk0 + (t>=1024 ? chunk1 : 0), then hi/lo split
__global__ __launch_bounds__(256)
void split_sum_k(const float* __restrict__ c0, const float* __restrict__ c1,
                 f16* __restrict__ hi, f16* __restrict__ lo)
{
  const long i = ((long)blockIdx.x * 256 + threadIdx.x) * 8;
  const int t = (int)(i >> 11);
  const float4 a = *(const float4*)(c0 + i);
  const float4 b = *(const float4*)(c0 + i + 4);
  float4 ca = {0,0,0,0}, cb = {0,0,0,0};
  if (t >= 1024) { ca = *(const float4*)(c1 + i); cb = *(const float4*)(c1 + i + 4); }
  const float vals[8] = {a.x+ca.x, a.y+ca.y, a.z+ca.z, a.w+ca.w,
                         b.x+cb.x, b.y+cb.y, b.z+cb.z, b.w+cb.w};
  f16x8 hv, lv;
#pragma unroll
  for (int j = 0; j < 8; j++) { const f16 h = (f16)vals[j]; hv[j] = h; lv[j] = (f16)(vals[j] - (float)h); }
  *(f16x8*)(hi + i) = hv;
  *(f16x8*)(lo + i) = lv;
}

__global__ __launch_bounds__(256)
void conv_f16_k(const float* __restrict__ src, f16* __restrict__ dst)
{
  const long i = ((long)blockIdx.x * 256 + threadIdx.x) * 8;
  const float4 a = *(const float4*)(src + i);
  const float4 b = *(const float4*)(src + i + 4);
  f16x8 o;
  o[0]=(f16)a.x; o[1]=(f16)a.y; o[2]=(f16)a.z; o[3]=(f16)a.w;
  o[4]=(f16)b.x; o[5]=(f16)b.y; o[6]=(f16)b.z; o[7]=(f16)b.w;
  *(f16x8*)(dst + i) = o;
}

// out = h2 + w0*(c0[kk=0]+c1[kk=0]) + w1*(c0[kk=1]+c1[kk=1])
__global__ __launch_bounds__(256)
void combine_k(const float* __restrict__ h2, const float* __restrict__ c0,
               const float* __restrict__ c1, const float* __restrict__ tw,
               float* __restrict__ out)
{
  const long i = ((long)blockIdx.x * 256 + threadIdx.x) * 4;
  const int t = (int)(i >> 11);
  const float w0 = tw[t * 2], w1 = tw[t * 2 + 1];
  const float4 a   = *(const float4*)(h2 + i);
  const float4 p0a = *(const float4*)(c0 + i);
  const float4 p0b = *(const float4*)(c1 + i);
  const float4 p1a = *(const float4*)(c0 + (long)T_SEQ * HID + i);
  const float4 p1b = *(const float4*)(c1 + (long)T_SEQ * HID + i);
  float4 o;
  o.x = a.x + w0 * (p0a.x + p0b.x) + w1 * (p1a.x + p1b.x);
  o.y = a.y + w0 * (p0a.y + p0b.y) + w1 * (p1a.y + p1b.y);
  o.z = a.z + w0 * (p0a.z + p0b.z) + w1 * (p1a.z + p1b.z);
  o.w = a.w + w0 * (p0a.w + p0b.w) + w1 * (p1a.w + p1b.w);
  *(float4*)(out + i) = o;
}

// ---------------------------------------------------------------------------
extern "C" void kernel_launch(void* const* d_in, const int* in_sizes, int n_in,
                              void* d_out, int out_size, void* d_ws, size_t ws_size,
                              hipStream_t stream)
{
  const float* x    = (const float*)d_in[0];
  const int*   pos  = (const int*)d_in[1];
  const float* n1w  = (const float*)d_in[2];
  const float* n2w  = (const float*)d_in[3];
  const float* wqkv = (const float*)d_in[4];
  const float* wo   = (const float*)d_in[5];
  const float* gw   = (const float*)d_in[6];
  const float* w1   = (const float*)d_in[7];
  const float* w2   = (const float*)d_in[8];
  const float* w3   = (const float*)d_in[9];
  float* out = (float*)d_out;

  char* base = (char*)d_ws;
  size_t off = 0;
  auto alloc = [&](size_t bytes) -> char* {
    char* r = base + off;
    off += (bytes + 255) & ~(size_t)255;
    return r;
  };
  f16* w1h = (f16*)alloc((size_t)NEXP * FFN_D * HID * 2);
  f16* w3h = (f16*)alloc((size_t)NEXP * FFN_D * HID * 2);
  f16* w2h = (f16*)alloc((size_t)NEXP * FFN_D * HID * 2);
  f16* wqh = (f16*)alloc((size_t)3072 * HID * 2);
  f16* wql = (f16*)alloc((size_t)3072 * HID * 2);
  f16* woh = (f16*)alloc((size_t)HID * HID * 2);
  f16* wol = (f16*)alloc((size_t)HID * HID * 2);
  f16* qh  = (f16*)alloc((size_t)NQH * T_SEQ * HD * 2);
  f16* ql  = (f16*)alloc((size_t)NQH * T_SEQ * HD * 2);
  f16* kh  = (f16*)alloc((size_t)NKV * T_SEQ * HD * 2);
  f16* kl  = (f16*)alloc((size_t)NKV * T_SEQ * HD * 2);
  f16* vh  = (f16*)alloc((size_t)NKV * T_SEQ * HD * 2);
  f16* vl  = (f16*)alloc((size_t)NKV * T_SEQ * HD * 2);
  float* h2      = (float*)alloc((size_t)T_SEQ * HID * 4);
  f16*   h2n     = (f16*)alloc((size_t)T_SEQ * HID * 2);
  float* contrib = (float*)alloc((size_t)2 * T_SEQ * HID * 4); // PV out (2 chunks) -> MoE contrib half0
  float* invr2 = (float*)alloc(T_SEQ * 4);
  int*   tidx  = (int*)alloc(T_SEQ * 2 * 4);
  float* twt   = (float*)alloc(T_SEQ * 2 * 4);
  int*   counts = (int*)alloc(256);   // (kept for layout stability; unused)
  int*   goff   = (int*)alloc(256);   // [0..8]
  int*   arows  = (int*)alloc(2 * T_SEQ * 4);
  int*   crows  = (int*)alloc(2 * T_SEQ * 4);
  (void)counts;
  // unions (lifetime-disjoint)
  char* uA = alloc((size_t)T_SEQ * 3072 * 4);      // qkv f32
  float* qkvf = (float*)uA;
  char* uB = alloc((size_t)T_SEQ * HID * 2);       // h hi -> attn hi
  f16* hh = (f16*)uB; f16* ahh = (f16*)uB;
  char* uC = alloc((size_t)T_SEQ * HID * 2);       // h lo -> attn lo
  f16* hl = (f16*)uC; f16* ahl = (f16*)uC;
  char* uS = alloc((size_t)8 * T_SEQ * T_SEQ * 4); // S (8 heads) -> h1/h3/g + contrib half1
  float* Sbuf = (float*)uS;
  f16* h1b = (f16*)uS;
  f16* h3b = (f16*)(uS + (size_t)2 * T_SEQ * FFN_D * 2);
  f16* gb  = (f16*)(uS + (size_t)4 * T_SEQ * FFN_D * 2);
  float* contribH = (float*)(uS + (size_t)6 * T_SEQ * FFN_D * 2);

  if (off > ws_size) return;

  // --- weight conversions
  conv_f16_k<<<(NEXP * FFN_D * HID) / (256 * 8), 256, 0, stream>>>(w1, w1h);
  conv_f16_k<<<(NEXP * FFN_D * HID) / (256 * 8), 256, 0, stream>>>(w3, w3h);
  conv_f16_k<<<(NEXP * FFN_D * HID) / (256 * 8), 256, 0, stream>>>(w2, w2h);
  split_pair_k<<<(3072 * HID) / (256 * 8), 256, 0, stream>>>(wqkv, wqh, wql);
  split_pair_k<<<(HID * HID) / (256 * 8), 256, 0, stream>>>(wo, woh, wol);

  // --- norm1 + fused 3-term QKV
  rmsnorm_k<true><<<T_SEQ, 256, 0, stream>>>(x, n1w, hh, hl, nullptr);
  gemm83<0,0,false><<<dim3(3072/128, T_SEQ/128, 1), 512, 0, stream>>>(
      hh, hl, wqh, wql, qkvf, HID, HID, HID, 3072, 0, 0, 0, 0, nullptr);
  rope_split_k<<<T_SEQ, 256, 0, stream>>>(qkvf, pos, qh, ql, kh, kl, vh, vl);

  // --- attention, two groups of 8 heads (S buffer reused)
  for (int grp = 0; grp < 2; grp++) {
    const f16* qh_g = qh + (size_t)grp * 8 * T_SEQ * HD;
    const f16* ql_g = ql + (size_t)grp * 8 * T_SEQ * HD;
    const f16* kh_g = kh + (size_t)grp * 2 * T_SEQ * HD;
    const f16* kl_g = kl + (size_t)grp * 2 * T_SEQ * HD;
    const f16* vh_g = vh + (size_t)grp * 2 * HD * T_SEQ;
    const f16* vl_g = vl + (size_t)grp * 2 * HD * T_SEQ;
    float* attn_g = contrib + (size_t)grp * 8 * HD;   // column offset within [T][2048]
    gemm83<0,1,false><<<dim3(T_SEQ/128, T_SEQ/128, 8), 512, 0, stream>>>(
        qh_g, ql_g, kh_g, kl_g, Sbuf, HD, HD, HD, T_SEQ,
        (long)T_SEQ * HD, (long)T_SEQ * HD, 4, (long)T_SEQ * T_SEQ, nullptr);
    softmax_pack<<<8 * T_SEQ / 4, 256, 0, stream>>>(Sbuf);
    gemm83<0,0,true><<<dim3(1, T_SEQ/128, 16), 512, 0, stream>>>(
        (const f16*)Sbuf, (const f16*)Sbuf + T_SEQ, vh_g, vl_g, attn_g,
        T_SEQ, 2 * T_SEQ, T_SEQ, HID,
        (long)T_SEQ * 2 * T_SEQ, (long)HD * T_SEQ, 4, HD, nullptr);
  }

  // --- attn chunk-sum + hi/lo split, then fused 3-term wo projection (+resid)
  split_sum_k<<<(T_SEQ * HID) / (256 * 8), 256, 0, stream>>>(contrib, contrib + (size_t)T_SEQ * HID, ahh, ahl);
  gemm83<2,0,false><<<dim3(HID/128, T_SEQ/128, 1), 512, 0, stream>>>(
      ahh, ahl, woh, wol, h2, HID, HID, HID, HID, 0, 0, 0, 0, x);

  // --- norm2, gate (f32), routing (single-block build)
  rmsnorm_k<false><<<T_SEQ, 256, 0, stream>>>(h2, n2w, h2n, nullptr, invr2);
  gate_topk<<<T_SEQ, 256, 0, stream>>>(h2, invr2, n2w, gw, tidx, twt);
  route_build<<<1, 256, 0, stream>>>(tidx, goff, arows, crows);

  // --- MoE expert GEMMs (grouped f16, 128^2/BK32/4-wave, 4 blocks/CU)
  gemm8<true,false,3,2><<<dim3(FFN_D/128, 16, 2 * NEXP), 256, 0, stream>>>(
      h2n, w1h, w3h, h1b, h3b, HID, HID, HID, FFN_D, (long)FFN_D * HID, goff, arows, nullptr);
  silu_mul_k<<<(2 * T_SEQ * FFN_D) / (256 * 8), 256, 0, stream>>>(h1b, h3b, gb);
  gemm8<false,true,0,1><<<dim3(HID/128, 16, 2 * NEXP), 256, 0, stream>>>(
      gb, w2h, nullptr, contrib, contribH, FFN_D, FFN_D, FFN_D, HID, (long)HID * FFN_D, goff, nullptr, crows);
  combine_k<<<(T_SEQ * HID) / (256 * 4), 256, 0, stream>>>(h2, contrib, contribH, twt, out);
}

// Round 11
// 936.876 us; speedup vs baseline: 1.0655x; 1.0655x over previous
//
#include <hip/hip_runtime.h>
#include <math.h>

typedef __fp16 f16;
typedef __fp16 f16x8 __attribute__((ext_vector_type(8)));
typedef __fp16 f16x4 __attribute__((ext_vector_type(4)));
typedef float  f32x4 __attribute__((ext_vector_type(4)));

#define T_SEQ 2048
#define HID   2048
#define NQH   16
#define NKV   4
#define HD    128
#define FFN_D 4096
#define NEXP  8

// async global->LDS DMA, 16B per lane; LDS dest is wave-uniform base (+lane*16 in HW)
#define GLDS(gp, lp) __builtin_amdgcn_global_load_lds( \
    (const __attribute__((address_space(1))) void*)(gp), \
    (__attribute__((address_space(3))) void*)(lp), 16, 0, 0)

__device__ __forceinline__ float wredsum(float v){
#pragma unroll
  for (int m = 32; m; m >>= 1) v += __shfl_xor(v, m, 64);
  return v;
}
__device__ __forceinline__ float wredmax(float v){
#pragma unroll
  for (int m = 32; m; m >>= 1) v = fmaxf(v, __shfl_xor(v, m, 64));
  return v;
}

// ---------------------------------------------------------------------------
// Fused MoE FFN-up: G = silu(A*B1^T) * (A*B3^T), grouped per expert.
// 4-wave 128x128 (BK=32), 48KB LDS (A|B1|B3 x 2 bufs), counted vmcnt(6) 2-deep.
// Eliminates h1/h3 materialization + separate silu pass. IDENTITY block map.
// Swizzle: granule g' = g ^ ((row>>1)&3) on source; read cp = (fq^((fr>>1)&3))*8.
// ---------------------------------------------------------------------------
template<bool GATHER_A>
__global__ __launch_bounds__(256, 2)
void gemm_ffn(const f16* __restrict__ A, const f16* __restrict__ B1,
              const f16* __restrict__ B3, f16* __restrict__ G,
              int K, int lda, int ldb, int ldg, long sBz,
              const int* __restrict__ grp_off, const int* __restrict__ a_rows)
{
  __shared__ __align__(16) f16 Lds[2][12288];  // A @0 | B1 @4096 | B3 @8192
  const int bn = blockIdx.x, bm = blockIdx.y, e = blockIdx.z;
  const int rowBase  = grp_off[e];
  const int rowCount = grp_off[e + 1] - rowBase;
  if (rowCount <= 0 || bm * 128 >= rowCount) return;
  const f16* B1z = B1 + (long)e * sBz;
  const f16* B3z = B3 + (long)e * sBz;
  const int nt = K >> 5;

  const int tid = threadIdx.x, lane = tid & 63, w = tid >> 6;
  const int wr = w >> 1, wc = w & 1;

  const int srow = tid >> 2;
  const int scol = (((tid & 3) ^ ((tid >> 3) & 3)) << 3);
  int aoff[2], boff[2];
#pragma unroll
  for (int i = 0; i < 2; i++) {
    int r = bm * 128 + i * 64 + srow;
    if (r > rowCount - 1) r = rowCount - 1;
    const int ar = GATHER_A ? a_rows[rowBase + r] : (rowBase + r);
    aoff[i] = ar * lda + scol;
    boff[i] = (bn * 128 + i * 64 + srow) * ldb + scol;
  }

#define STGF(buf, kk) do { f16* _l = &Lds[buf][0]; \
  GLDS(A   + aoff[0] + (kk), _l +         w * 512); \
  GLDS(A   + aoff[1] + (kk), _l +  2048 + w * 512); \
  GLDS(B1z + boff[0] + (kk), _l +  4096 + w * 512); \
  GLDS(B1z + boff[1] + (kk), _l +  6144 + w * 512); \
  GLDS(B3z + boff[0] + (kk), _l +  8192 + w * 512); \
  GLDS(B3z + boff[1] + (kk), _l + 10240 + w * 512); } while (0)

  const int fr = lane & 15, fq = lane >> 4;
  const int cp = ((fq ^ ((fr >> 1) & 3)) << 3);
  const int aRow  = (wr * 64 + fr) * 32;
  const int b1Row = 4096 + (wc * 64 + fr) * 32;
  const int b3Row = 8192 + (wc * 64 + fr) * 32;

  f32x4 acc1[4][4] = {};
  f32x4 acc3[4][4] = {};

  STGF(0, 0);
  if (nt > 1) STGF(1, 32);

  for (int kt = 0; kt < nt; kt++) {
    if (kt + 1 < nt) asm volatile("s_waitcnt vmcnt(6)" ::: "memory");
    else             asm volatile("s_waitcnt vmcnt(0)" ::: "memory");
    __builtin_amdgcn_s_barrier();
    const f16* Lb = &Lds[kt & 1][0];
    f16x8 af[4], b1f[4], b3f[4];
#pragma unroll
    for (int m = 0; m < 4; m++) af[m]  = *(const f16x8*)(Lb + aRow  + m * 512 + cp);
#pragma unroll
    for (int n = 0; n < 4; n++) b1f[n] = *(const f16x8*)(Lb + b1Row + n * 512 + cp);
#pragma unroll
    for (int n = 0; n < 4; n++) b3f[n] = *(const f16x8*)(Lb + b3Row + n * 512 + cp);
    asm volatile("s_waitcnt lgkmcnt(0)" ::: "memory");
    __builtin_amdgcn_sched_barrier(0);
    __builtin_amdgcn_s_barrier();                 // all reads done -> safe to restage
    if (kt + 2 < nt) STGF(kt & 1, (kt + 2) * 32);
    __builtin_amdgcn_s_setprio(1);
#pragma unroll
    for (int m = 0; m < 4; m++)
#pragma unroll
      for (int n = 0; n < 4; n++) {
        acc1[m][n] = __builtin_amdgcn_mfma_f32_16x16x32_f16(af[m], b1f[n], acc1[m][n], 0, 0, 0);
        acc3[m][n] = __builtin_amdgcn_mfma_f32_16x16x32_f16(af[m], b3f[n], acc3[m][n], 0, 0, 0);
      }
    __builtin_amdgcn_s_setprio(0);
  }
#undef STGF

  const int ccol0 = bn * 128 + wc * 64 + fr;
#pragma unroll
  for (int m = 0; m < 4; m++) {
#pragma unroll
    for (int r = 0; r < 4; r++) {
      const int g = bm * 128 + wr * 64 + m * 16 + fq * 4 + r;
      if (g >= rowCount) continue;
      const long orow = rowBase + g;
#pragma unroll
      for (int n = 0; n < 4; n++) {
        const float h1 = acc1[m][n][r];
        const float h3 = acc3[m][n][r];
        const float s  = h1 / (1.0f + __expf(-h1));
        G[orow * ldg + (ccol0 + n * 16)] = (f16)(s * h3);
      }
    }
  }
}

// ---------------------------------------------------------------------------
// 4-wave 128x128 (BK=32) grouped f16 GEMM (r10 schedule). Used for w2.
// EPI: 0 = f32 store, 3 = f16 store, 4 = f16 store of tw[token,rank]*acc.
// MODE: 0 plain; 1 split-K (z = expert*2 + Khalf, half1 -> Cv2).
// ---------------------------------------------------------------------------
template<bool GATHER_A, bool SCATTER_C, int EPI, int MODE>
__global__ __launch_bounds__(256, 4)
void gemm8(const f16* __restrict__ A, const f16* __restrict__ B,
           void* __restrict__ Cv, void* __restrict__ Cv2,
           int K, int lda, int ldb, int ldc, long sBz,
           const int* __restrict__ grp_off, const int* __restrict__ a_rows,
           const int* __restrict__ c_rows, const float* __restrict__ tw)
{
  __shared__ __align__(16) f16 Lds[2][8192];   // A[128][32] @0 | B[128][32] @4096
  const int bn = blockIdx.x, bm = blockIdx.y, z = blockIdx.z;
  int e = z, half = 0;
  if (MODE == 1) { e = z >> 1; half = z & 1; }
  const int rowBase  = grp_off[e];
  const int rowCount = grp_off[e + 1] - rowBase;
  if (rowCount <= 0 || bm * 128 >= rowCount) return;
  const f16* Bz = B + (long)e * sBz;
  int k0 = 0, kN = K;
  if (MODE == 1) { kN = K >> 1; k0 = half * kN; }
  const int nt = kN >> 5;

  const int tid = threadIdx.x, lane = tid & 63, w = tid >> 6;
  const int wr = w >> 1, wc = w & 1;

  const int srow = tid >> 2;
  const int scol = (((tid & 3) ^ ((tid >> 3) & 3)) << 3);
  int aoff[2], boff[2];
#pragma unroll
  for (int i = 0; i < 2; i++) {
    int r = bm * 128 + i * 64 + srow;
    if (r > rowCount - 1) r = rowCount - 1;
    const int ar = GATHER_A ? a_rows[rowBase + r] : (rowBase + r);
    aoff[i] = ar * lda + scol + k0;
    boff[i] = (bn * 128 + i * 64 + srow) * ldb + scol + k0;
  }

#define STG8(buf, kk) do { f16* _l = &Lds[buf][0]; \
  GLDS(A  + aoff[0] + (kk), _l +        w * 512); \
  GLDS(A  + aoff[1] + (kk), _l + 2048 + w * 512); \
  GLDS(Bz + boff[0] + (kk), _l + 4096 + w * 512); \
  GLDS(Bz + boff[1] + (kk), _l + 6144 + w * 512); } while (0)

  const int fr = lane & 15, fq = lane >> 4;
  const int cp = ((fq ^ ((fr >> 1) & 3)) << 3);
  const int aRow = (wr * 64 + fr) * 32;
  const int bRow = 4096 + (wc * 64 + fr) * 32;

  f32x4 acc[4][4] = {};

  STG8(0, 0);
  if (nt > 1) STG8(1, 32);

  for (int kt = 0; kt < nt; kt++) {
    if (kt + 1 < nt) asm volatile("s_waitcnt vmcnt(4)" ::: "memory");
    else             asm volatile("s_waitcnt vmcnt(0)" ::: "memory");
    __builtin_amdgcn_s_barrier();
    const f16* Lb = &Lds[kt & 1][0];
    f16x8 bf[4], af[4];
#pragma unroll
    for (int n = 0; n < 4; n++) bf[n] = *(const f16x8*)(Lb + bRow + n * 512 + cp);
#pragma unroll
    for (int m = 0; m < 4; m++) af[m] = *(const f16x8*)(Lb + aRow + m * 512 + cp);
    asm volatile("s_waitcnt lgkmcnt(0)" ::: "memory");
    __builtin_amdgcn_sched_barrier(0);
    __builtin_amdgcn_s_barrier();                 // all reads of buf done -> safe to restage
    if (kt + 2 < nt) STG8(kt & 1, (kt + 2) * 32);
    __builtin_amdgcn_s_setprio(1);
#pragma unroll
    for (int m = 0; m < 4; m++)
#pragma unroll
      for (int n = 0; n < 4; n++)
        acc[m][n] = __builtin_amdgcn_mfma_f32_16x16x32_f16(af[m], bf[n], acc[m][n], 0, 0, 0);
    __builtin_amdgcn_s_setprio(0);
  }
#undef STG8

  float* Cf = (MODE == 1 && half) ? (float*)Cv2 : (float*)Cv;
  f16*   Ch = (MODE == 1 && half) ? (f16*)Cv2   : (f16*)Cv;
  const int ccol0 = bn * 128 + wc * 64 + fr;
#pragma unroll
  for (int m = 0; m < 4; m++) {
#pragma unroll
    for (int r = 0; r < 4; r++) {
      const int g = bm * 128 + wr * 64 + m * 16 + fq * 4 + r;
      if (g >= rowCount) continue;
      const long orow = SCATTER_C ? (long)c_rows[rowBase + g] : (long)(rowBase + g);
#pragma unroll
      for (int n = 0; n < 4; n++) {
        const long idx = orow * ldc + (ccol0 + n * 16);
        if (EPI == 4) {
          const int t = (int)(orow & (T_SEQ - 1)), kk = (int)(orow >> 11);
          Ch[idx] = (f16)(tw[t * 2 + kk] * acc[m][n][r]);
        }
        else if (EPI == 3) Ch[idx] = (f16)acc[m][n][r];
        else               Cf[idx] = acc[m][n][r];
      }
    }
  }
}

// ---------------------------------------------------------------------------
// 8-wave 128x128 (BK=64) fused hi/lo 3-term GEMM, counted 2-deep schedule:
//   C = Ah*Bh^T + Ah*Bl^T + Al*Bh^T   (fp32-faithful)
// IDENTITY block mapping. LDS 2 x 64KB (Ah|Al|Bh|Bl x 128x64).
// EPI: 0 f32, 2 f32+resid. CAUSAL: skip bn>bm.
// PVK: z = head | chunk<<3; K causally limited to (bm+1)*128; C += chunk*T*HID.
// ---------------------------------------------------------------------------
template<int EPI, int CAUSAL, bool PVK>
__global__ __launch_bounds__(512, 2)
void gemm83(const f16* __restrict__ Ah, const f16* __restrict__ Al,
            const f16* __restrict__ Bh, const f16* __restrict__ Bl,
            void* __restrict__ Cv, int K, int lda, int ldb, int ldc,
            long sAz, long sBz, int bdiv, long sCz,
            const float* __restrict__ resid)
{
  __shared__ __align__(16) f16 Lds[2][32768];  // Ah 0 | Al 8192 | Bh 16384 | Bl 24576
  const int bn = blockIdx.x, bm = blockIdx.y, z = blockIdx.z;
  if (CAUSAL == 1 && bn > bm) return;
  int head = z, chunk = 0;
  if (PVK) { head = z & 7; chunk = z >> 3; }
  int kstart = 0, kend = K;
  if (PVK) {
    const int km = (bm + 1) * 128;
    if (km < kend) kend = km;
    kstart = chunk * 1024;
    if (kstart >= kend) return;
    if (kend > kstart + 1024) kend = kstart + 1024;
  }
  const int nt = (kend - kstart) >> 6;

  const f16* Ahz = Ah + (long)head * sAz;
  const f16* Alz = Al + (long)head * sAz;
  const long zb = (long)(bdiv ? head / bdiv : head) * sBz;
  const f16* Bhz = Bh + zb;
  const f16* Blz = Bl + zb;

  const int tid = threadIdx.x, lane = tid & 63, w = tid >> 6;
  const int wr = w >> 2, wc = w & 3;

  const int srow = w * 8 + (lane >> 3);
  const int scol = (((lane & 7) ^ (lane >> 3)) << 3);
  long ar[2], br[2];
#pragma unroll
  for (int i = 0; i < 2; i++) {
    ar[i] = (long)(bm * 128 + i * 64 + srow) * lda + scol + kstart;
    br[i] = (long)(bn * 128 + i * 64 + srow) * ldb + scol + kstart;
  }

#define STG83(buf, kk) do { f16* _l = &Lds[buf][0]; \
  GLDS(Ahz + ar[0] + (kk), _l +         w * 512); GLDS(Ahz + ar[1] + (kk), _l +  4096 + w * 512); \
  GLDS(Alz + ar[0] + (kk), _l +  8192 + w * 512); GLDS(Alz + ar[1] + (kk), _l + 12288 + w * 512); \
  GLDS(Bhz + br[0] + (kk), _l + 16384 + w * 512); GLDS(Bhz + br[1] + (kk), _l + 20480 + w * 512); \
  GLDS(Blz + br[0] + (kk), _l + 24576 + w * 512); GLDS(Blz + br[1] + (kk), _l + 28672 + w * 512); } while (0)

  const int fr = lane & 15, fq = lane >> 4;
  const int cp0 = ((fq       ^ (fr & 7)) << 3);
  const int cp1 = (((4 | fq) ^ (fr & 7)) << 3);
  const int aRow = (wr * 64 + fr) * 64;           // + m*1024 ; Al at +8192
  const int bRow = 16384 + (wc * 32 + fr) * 64;   // + n*1024 ; Bl at +8192

  f32x4 acc[4][2] = {};

  STG83(0, 0);
  if (nt > 1) STG83(1, 64);

  for (int kt = 0; kt < nt; kt++) {
    if (kt + 1 < nt) asm volatile("s_waitcnt vmcnt(8)" ::: "memory");
    else             asm volatile("s_waitcnt vmcnt(0)" ::: "memory");
    __builtin_amdgcn_s_barrier();
    const f16* Lb = &Lds[kt & 1][0];
#pragma unroll
    for (int ks = 0; ks < 2; ks++) {
      const int cp = ks ? cp1 : cp0;
      f16x8 ah[4], al[4], bh[2], bl[2];
#pragma unroll
      for (int n = 0; n < 2; n++) {
        bh[n] = *(const f16x8*)(Lb + bRow +        n * 1024 + cp);
        bl[n] = *(const f16x8*)(Lb + bRow + 8192 + n * 1024 + cp);
      }
#pragma unroll
      for (int m = 0; m < 4; m++) {
        ah[m] = *(const f16x8*)(Lb + aRow +        m * 1024 + cp);
        al[m] = *(const f16x8*)(Lb + aRow + 8192 + m * 1024 + cp);
      }
      __builtin_amdgcn_s_setprio(1);
#pragma unroll
      for (int m = 0; m < 4; m++)
#pragma unroll
        for (int n = 0; n < 2; n++) {
          acc[m][n] = __builtin_amdgcn_mfma_f32_16x16x32_f16(ah[m], bh[n], acc[m][n], 0, 0, 0);
          acc[m][n] = __builtin_amdgcn_mfma_f32_16x16x32_f16(ah[m], bl[n], acc[m][n], 0, 0, 0);
          acc[m][n] = __builtin_amdgcn_mfma_f32_16x16x32_f16(al[m], bh[n], acc[m][n], 0, 0, 0);
        }
      __builtin_amdgcn_s_setprio(0);
    }
    __builtin_amdgcn_s_barrier();
    if (kt + 2 < nt) STG83(kt & 1, (kt + 2) * 64);
  }
#undef STG83

  float* Cf = (float*)Cv + (long)head * sCz + (PVK ? (long)chunk * T_SEQ * HID : 0);
  const int crow0 = bm * 128 + wr * 64 + fq * 4;
  const int ccol0 = bn * 128 + wc * 32 + fr;
#pragma unroll
  for (int m = 0; m < 4; m++) {
#pragma unroll
    for (int r = 0; r < 4; r++) {
      const long row = crow0 + m * 16 + r;
#pragma unroll
      for (int n = 0; n < 2; n++) {
        const long idx = row * ldc + (ccol0 + n * 16);
        const float v = acc[m][n][r];
        if (EPI == 2) Cf[idx] = v + resid[idx];
        else          Cf[idx] = v;
      }
    }
  }
}

// ---------------------------------------------------------------------------
template<bool SPLIT>
__global__ __launch_bounds__(256)
void rmsnorm_k(const float* __restrict__ x, const float* __restrict__ w,
               f16* __restrict__ hi, f16* __restrict__ lo, float* __restrict__ invr_out)
{
  const int t = blockIdx.x, tid = threadIdx.x;
  const float4* xr = (const float4*)(x + (long)t * HID);
  const float4 a = xr[tid * 2], b = xr[tid * 2 + 1];
  float ss = a.x*a.x + a.y*a.y + a.z*a.z + a.w*a.w
           + b.x*b.x + b.y*b.y + b.z*b.z + b.w*b.w;
  ss = wredsum(ss);
  __shared__ float red[4];
  if ((tid & 63) == 0) red[tid >> 6] = ss;
  __syncthreads();
  const float tot  = red[0] + red[1] + red[2] + red[3];
  const float invr = 1.0f / sqrtf(tot * (1.0f / HID) + 1e-5f);
  if (invr_out && tid == 0) invr_out[t] = invr;
  const float4* wr4 = (const float4*)w;
  const float4 wa = wr4[tid * 2], wb = wr4[tid * 2 + 1];
  const float vals[8] = { a.x*wa.x, a.y*wa.y, a.z*wa.z, a.w*wa.w,
                          b.x*wb.x, b.y*wb.y, b.z*wb.z, b.w*wb.w };
  f16x8 hv, lv;
#pragma unroll
  for (int j = 0; j < 8; j++) {
    const float y = vals[j] * invr;
    const f16 h = (f16)y;
    hv[j] = h;
    if (SPLIT) lv[j] = (f16)(y - (float)h);
  }
  const long base = (long)t * HID + tid * 8;
  *(f16x8*)(hi + base) = hv;
  if (SPLIT) *(f16x8*)(lo + base) = lv;
}

// RoPE + hi/lo split; q -> (h,T,128), k -> (g,T,128), v -> transposed (g,128,T)
__global__ __launch_bounds__(256)
void rope_split_k(const float* __restrict__ qkv, const int* __restrict__ pos,
                  f16* __restrict__ qh, f16* __restrict__ ql,
                  f16* __restrict__ kh, f16* __restrict__ kl,
                  f16* __restrict__ vh, f16* __restrict__ vl)
{
  const int t = blockIdx.x, tid = threadIdx.x;
  __shared__ float invf[64];
  if (tid < 64) {
    const float y = (float)tid * (1.0f / 64.0f);
    invf[tid] = 1.0f / (float)pow(10000.0, (double)y);   // f32-rounded exact pow
  }
  __syncthreads();
  const float p = (float)pos[t];
  const float* row = qkv + (long)t * 3072;

#pragma unroll
  for (int i = 0; i < 4; i++) {
    const int pi = tid + i * 256;
    const int h = pi >> 6, d = pi & 63;
    const float ang = p * invf[d];
    float s, c; sincosf(ang, &s, &c);
    const float x1 = row[h * 128 + d], x2 = row[h * 128 + 64 + d];
    const float o1 = x1 * c - x2 * s;
    const float o2 = x2 * c + x1 * s;
    const long base = ((long)h * T_SEQ + t) * HD;
    { const f16 hh = (f16)o1; qh[base + d]      = hh; ql[base + d]      = (f16)(o1 - (float)hh); }
    { const f16 hh = (f16)o2; qh[base + 64 + d] = hh; ql[base + 64 + d] = (f16)(o2 - (float)hh); }
  }
  {
    const int g = tid >> 6, d = tid & 63;
    const float ang = p * invf[d];
    float s, c; sincosf(ang, &s, &c);
    const float x1 = row[2048 + g * 128 + d], x2 = row[2048 + g * 128 + 64 + d];
    const float o1 = x1 * c - x2 * s;
    const float o2 = x2 * c + x1 * s;
    const long base = ((long)g * T_SEQ + t) * HD;
    { const f16 hh = (f16)o1; kh[base + d]      = hh; kl[base + d]      = (f16)(o1 - (float)hh); }
    { const f16 hh = (f16)o2; kh[base + 64 + d] = hh; kl[base + 64 + d] = (f16)(o2 - (float)hh); }
  }
#pragma unroll
  for (int i = 0; i < 2; i++) {
    const int e = tid + i * 256;
    const int g = e >> 7, d = e & 127;
    const float v = row[2560 + e];
    const long idx = ((long)g * HD + d) * T_SEQ + t;
    const f16 h = (f16)v; vh[idx] = h; vl[idx] = (f16)(v - (float)h);
  }
}

// Row softmax over f32 scores, causal mask, pack P as [hi f16 x 2048 | lo f16 x 2048]
// in place. Causal-bounded: row t touches only segments < (t>>8)+1.
__global__ __launch_bounds__(256)
void softmax_pack(float* __restrict__ S)
{
  const int row  = blockIdx.x * 4 + (threadIdx.x >> 6);
  const int lane = threadIdx.x & 63;
  const int t    = row & (T_SEQ - 1);
  const int nseg = (t >> 8) + 1;
  float* Sr = S + (long)row * T_SEQ;
  float4 v[8];
  const float4* Sr4 = (const float4*)Sr;
#pragma unroll
  for (int i = 0; i < 8; i++) if (i < nseg) v[i] = Sr4[i * 64 + lane];
  const float scale = 0.08838834764831843f; // 128^-0.5
  float vmax = -3.4e38f;
#pragma unroll
  for (int i = 0; i < 8; i++) {
    if (i >= nseg) continue;
    float* pv = (float*)&v[i];
    const int s0 = (i * 64 + lane) * 4;
#pragma unroll
    for (int j = 0; j < 4; j++) {
      const float xx = (s0 + j <= t) ? pv[j] * scale : -3.4e38f;
      pv[j] = xx;
      vmax = fmaxf(vmax, xx);
    }
  }
  vmax = wredmax(vmax);
  float sum = 0.f;
#pragma unroll
  for (int i = 0; i < 8; i++) {
    if (i >= nseg) continue;
    float* pv = (float*)&v[i];
#pragma unroll
    for (int j = 0; j < 4; j++) {
      const float e = (pv[j] > -3.0e38f) ? __expf(pv[j] - vmax) : 0.f;
      pv[j] = e; sum += e;
    }
  }
  sum = wredsum(sum);
  const float rinv = 1.0f / sum;
  __syncthreads();
  f16* P = (f16*)Sr;
#pragma unroll
  for (int i = 0; i < 8; i++) {
    if (i >= nseg) continue;
    const int s0 = (i * 64 + lane) * 4;
    float* pv = (float*)&v[i];
    f16x4 hv, lv;
#pragma unroll
    for (int j = 0; j < 4; j++) {
      const float pr = pv[j] * rinv;
      const f16 ph = (f16)pr;
      hv[j] = ph; lv[j] = (f16)(pr - (float)ph);
    }
    *(f16x4*)(P + s0)         = hv;
    *(f16x4*)(P + T_SEQ + s0) = lv;
  }
}

// Gate: f32 logits from f32 h2 (re-normalized), top-2 + renormalized weights.
__global__ __launch_bounds__(256)
void gate_topk(const float* __restrict__ h2, const float* __restrict__ invr,
               const float* __restrict__ n2w, const float* __restrict__ gw,
               int* __restrict__ top_idx, float* __restrict__ top_w)
{
  const int t = blockIdx.x, tid = threadIdx.x;
  const float r = invr[t];
  const float4* xr = (const float4*)(h2 + (long)t * HID);
  const float4 a = xr[tid * 2], b = xr[tid * 2 + 1];
  const float4* wr4 = (const float4*)n2w;
  const float4 wa = wr4[tid * 2], wb = wr4[tid * 2 + 1];
  const float hn[8] = { a.x*wa.x*r, a.y*wa.y*r, a.z*wa.z*r, a.w*wa.w*r,
                        b.x*wb.x*r, b.y*wb.y*r, b.z*wb.z*r, b.w*wb.w*r };
  float part[8];
#pragma unroll
  for (int e = 0; e < 8; e++) {
    const float4* g4 = (const float4*)(gw + (long)e * HID + tid * 8);
    const float4 ga = g4[0], gb = g4[1];
    part[e] = hn[0]*ga.x + hn[1]*ga.y + hn[2]*ga.z + hn[3]*ga.w
            + hn[4]*gb.x + hn[5]*gb.y + hn[6]*gb.z + hn[7]*gb.w;
  }
#pragma unroll
  for (int e = 0; e < 8; e++) part[e] = wredsum(part[e]);
  __shared__ float red[4][8];
  if ((tid & 63) == 0) {
#pragma unroll
    for (int e = 0; e < 8; e++) red[tid >> 6][e] = part[e];
  }
  __syncthreads();
  if (tid == 0) {
    float lg[8];
#pragma unroll
    for (int e = 0; e < 8; e++) lg[e] = red[0][e] + red[1][e] + red[2][e] + red[3][e];
    int i1 = 0;
    for (int e = 1; e < 8; e++) if (lg[e] > lg[i1]) i1 = e;
    int i2 = -1;
    for (int e = 0; e < 8; e++) { if (e == i1) continue; if (i2 < 0 || lg[e] > lg[i2]) i2 = e; }
    const float q = expf(lg[i2] - lg[i1]);
    top_idx[t * 2] = i1; top_idx[t * 2 + 1] = i2;
    top_w[t * 2]     = 1.0f / (1.0f + q);
    top_w[t * 2 + 1] = q / (1.0f + q);
  }
}

// Single-block routing build: count -> scan -> fill.
__global__ __launch_bounds__(256)
void route_build(const int* __restrict__ ti, int* __restrict__ goff,
                 int* __restrict__ arows, int* __restrict__ crows)
{
  __shared__ int cnt[8], cur[8], off[9];
  const int tid = threadIdx.x;
  if (tid < 8) { cnt[tid] = 0; cur[tid] = 0; }
  __syncthreads();
  for (int i = tid; i < 2 * T_SEQ; i += 256) atomicAdd(&cnt[ti[i]], 1);
  __syncthreads();
  if (tid == 0) {
    int s = 0;
    for (int e = 0; e < NEXP; e++) { off[e] = s; s += cnt[e]; }
    off[NEXP] = s;
    for (int e = 0; e <= NEXP; e++) goff[e] = off[e];
  }
  __syncthreads();
  for (int i = tid; i < 2 * T_SEQ; i += 256) {
    const int e = ti[i];
    const int p = atomicAdd(&cur[e], 1);
    const int slot = off[e] + p;
    arows[slot] = i >> 1;
    crows[slot] = (i & 1) * T_SEQ + (i >> 1);
  }
}

__global__ __launch_bounds__(256)
void split_pair_k(const float* __restrict__ src, f16* __restrict__ hi, f16* __restrict__ lo)
{
  const long i = ((long)blockIdx.x * 256 + threadIdx.x) * 8;
  const float4 a = *(const float4*)(src + i);
  const float4 b = *(const float4*)(src + i + 4);
  const float vals[8] = {a.x,a.y,a.z,a.w,b.x,b.y,b.z,b.w};
  f16x8 hv, lv;
#pragma unroll
  for (int j = 0; j < 8; j++) { const f16 h = (f16)vals[j]; hv[j] = h; lv[j] = (f16)(vals[j] - (float)h); }
  *(f16x8*)(hi + i) = hv;
  *(f16x8*)(lo + i) = lv;
}

// attn = chunk0 + (t>=1024 ? chunk1 : 0), then hi/lo split
__global__ __launch_bounds__(256)
void split_sum_k(const float* __restrict__ c0, const float* __restrict__ c1,
                 f16* __restrict__ hi, f16* __restrict__ lo)
{
  const long i = ((long)blockIdx.x * 256 + threadIdx.x) * 8;
  const int t = (int)(i >> 11);
  const float4 a = *(const float4*)(c0 + i);
  const float4 b = *(const float4*)(c0 + i + 4);
  float4 ca = {0,0,0,0}, cb = {0,0,0,0};
  if (t >= 1024) { ca = *(const float4*)(c1 + i); cb = *(const float4*)(c1 + i + 4); }
  const float vals[8] = {a.x+ca.x, a.y+ca.y, a.z+ca.z, a.w+ca.w,
                         b.x+cb.x, b.y+cb.y, b.z+cb.z, b.w+cb.w};
  f16x8 hv, lv;
#pragma unroll
  for (int j = 0; j < 8; j++) { const f16 h = (f16)vals[j]; hv[j] = h; lv[j] = (f16)(vals[j] - (float)h); }
  *(f16x8*)(hi + i) = hv;
  *(f16x8*)(lo + i) = lv;
}

__global__ __launch_bounds__(256)
void conv_f16_k(const float* __restrict__ src, f16* __restrict__ dst)
{
  const long i = ((long)blockIdx.x * 256 + threadIdx.x) * 8;
  const float4 a = *(const float4*)(src + i);
  const float4 b = *(const float4*)(src + i + 4);
  f16x8 o;
  o[0]=(f16)a.x; o[1]=(f16)a.y; o[2]=(f16)a.z; o[3]=(f16)a.w;
  o[4]=(f16)b.x; o[5]=(f16)b.y; o[6]=(f16)b.z; o[7]=(f16)b.w;
  *(f16x8*)(dst + i) = o;
}

// out = h2 + c0[kk=0] + c1[kk=0] + c0[kk=1] + c1[kk=1]   (f16 contribs, pre-weighted)
__global__ __launch_bounds__(256)
void combine_k(const float* __restrict__ h2, const f16* __restrict__ c0,
               const f16* __restrict__ c1, float* __restrict__ out)
{
  const long i = ((long)blockIdx.x * 256 + threadIdx.x) * 4;
  const float4 a = *(const float4*)(h2 + i);
  const f16x4 p0 = *(const f16x4*)(c0 + i);
  const f16x4 p1 = *(const f16x4*)(c1 + i);
  const f16x4 q0 = *(const f16x4*)(c0 + (long)T_SEQ * HID + i);
  const f16x4 q1 = *(const f16x4*)(c1 + (long)T_SEQ * HID + i);
  float4 o;
  o.x = a.x + (float)p0[0] + (float)p1[0] + (float)q0[0] + (float)q1[0];
  o.y = a.y + (float)p0[1] + (float)p1[1] + (float)q0[1] + (float)q1[1];
  o.z = a.z + (float)p0[2] + (float)p1[2] + (float)q0[2] + (float)q1[2];
  o.w = a.w + (float)p0[3] + (float)p1[3] + (float)q0[3] + (float)q1[3];
  *(float4*)(out + i) = o;
}

// ---------------------------------------------------------------------------
extern "C" void kernel_launch(void* const* d_in, const int* in_sizes, int n_in,
                              void* d_out, int out_size, void* d_ws, size_t ws_size,
                              hipStream_t stream)
{
  const float* x    = (const float*)d_in[0];
  const int*   pos  = (const int*)d_in[1];
  const float* n1w  = (const float*)d_in[2];
  const float* n2w  = (const float*)d_in[3];
  const float* wqkv = (const float*)d_in[4];
  const float* wo   = (const float*)d_in[5];
  const float* gw   = (const float*)d_in[6];
  const float* w1   = (const float*)d_in[7];
  const float* w2   = (const float*)d_in[8];
  const float* w3   = (const float*)d_in[9];
  float* out = (float*)d_out;

  char* base = (char*)d_ws;
  size_t off = 0;
  auto alloc = [&](size_t bytes) -> char* {
    char* r = base + off;
    off += (bytes + 255) & ~(size_t)255;
    return r;
  };
  f16* w1h = (f16*)alloc((size_t)NEXP * FFN_D * HID * 2);
  f16* w3h = (f16*)alloc((size_t)NEXP * FFN_D * HID * 2);
  f16* w2h = (f16*)alloc((size_t)NEXP * FFN_D * HID * 2);
  f16* wqh = (f16*)alloc((size_t)3072 * HID * 2);
  f16* wql = (f16*)alloc((size_t)3072 * HID * 2);
  f16* woh = (f16*)alloc((size_t)HID * HID * 2);
  f16* wol = (f16*)alloc((size_t)HID * HID * 2);
  f16* qh  = (f16*)alloc((size_t)NQH * T_SEQ * HD * 2);
  f16* ql  = (f16*)alloc((size_t)NQH * T_SEQ * HD * 2);
  f16* kh  = (f16*)alloc((size_t)NKV * T_SEQ * HD * 2);
  f16* kl  = (f16*)alloc((size_t)NKV * T_SEQ * HD * 2);
  f16* vh  = (f16*)alloc((size_t)NKV * T_SEQ * HD * 2);
  f16* vl  = (f16*)alloc((size_t)NKV * T_SEQ * HD * 2);
  float* h2      = (float*)alloc((size_t)T_SEQ * HID * 4);
  f16*   h2n     = (f16*)alloc((size_t)T_SEQ * HID * 2);
  float* contrib = (float*)alloc((size_t)2 * T_SEQ * HID * 4); // PV out (2 chunks) -> MoE contrib (f16) half0
  float* invr2 = (float*)alloc(T_SEQ * 4);
  int*   tidx  = (int*)alloc(T_SEQ * 2 * 4);
  float* twt   = (float*)alloc(T_SEQ * 2 * 4);
  int*   counts = (int*)alloc(256);   // (layout stability; unused)
  int*   goff   = (int*)alloc(256);   // [0..8]
  int*   arows  = (int*)alloc(2 * T_SEQ * 4);
  int*   crows  = (int*)alloc(2 * T_SEQ * 4);
  (void)counts;
  // unions (lifetime-disjoint)
  char* uA = alloc((size_t)T_SEQ * 3072 * 4);      // qkv f32
  float* qkvf = (float*)uA;
  char* uB = alloc((size_t)T_SEQ * HID * 2);       // h hi -> attn hi
  f16* hh = (f16*)uB; f16* ahh = (f16*)uB;
  char* uC = alloc((size_t)T_SEQ * HID * 2);       // h lo -> attn lo
  f16* hl = (f16*)uC; f16* ahl = (f16*)uC;
  char* uS = alloc((size_t)8 * T_SEQ * T_SEQ * 4); // S (8 heads) -> gb + contribH
  float* Sbuf = (float*)uS;
  f16* gb  = (f16*)(uS + (size_t)4 * T_SEQ * FFN_D * 2);
  f16* contribH = (f16*)(uS + (size_t)6 * T_SEQ * FFN_D * 2);

  if (off > ws_size) return;

  // --- weight conversions
  conv_f16_k<<<(NEXP * FFN_D * HID) / (256 * 8), 256, 0, stream>>>(w1, w1h);
  conv_f16_k<<<(NEXP * FFN_D * HID) / (256 * 8), 256, 0, stream>>>(w3, w3h);
  conv_f16_k<<<(NEXP * FFN_D * HID) / (256 * 8), 256, 0, stream>>>(w2, w2h);
  split_pair_k<<<(3072 * HID) / (256 * 8), 256, 0, stream>>>(wqkv, wqh, wql);
  split_pair_k<<<(HID * HID) / (256 * 8), 256, 0, stream>>>(wo, woh, wol);

  // --- norm1 + fused 3-term QKV
  rmsnorm_k<true><<<T_SEQ, 256, 0, stream>>>(x, n1w, hh, hl, nullptr);
  gemm83<0,0,false><<<dim3(3072/128, T_SEQ/128, 1), 512, 0, stream>>>(
      hh, hl, wqh, wql, qkvf, HID, HID, HID, 3072, 0, 0, 0, 0, nullptr);
  rope_split_k<<<T_SEQ, 256, 0, stream>>>(qkvf, pos, qh, ql, kh, kl, vh, vl);

  // --- attention, two groups of 8 heads (S buffer reused)
  for (int grp = 0; grp < 2; grp++) {
    const f16* qh_g = qh + (size_t)grp * 8 * T_SEQ * HD;
    const f16* ql_g = ql + (size_t)grp * 8 * T_SEQ * HD;
    const f16* kh_g = kh + (size_t)grp * 2 * T_SEQ * HD;
    const f16* kl_g = kl + (size_t)grp * 2 * T_SEQ * HD;
    const f16* vh_g = vh + (size_t)grp * 2 * HD * T_SEQ;
    const f16* vl_g = vl + (size_t)grp * 2 * HD * T_SEQ;
    float* attn_g = contrib + (size_t)grp * 8 * HD;   // column offset within [T][2048]
    gemm83<0,1,false><<<dim3(T_SEQ/128, T_SEQ/128, 8), 512, 0, stream>>>(
        qh_g, ql_g, kh_g, kl_g, Sbuf, HD, HD, HD, T_SEQ,
        (long)T_SEQ * HD, (long)T_SEQ * HD, 4, (long)T_SEQ * T_SEQ, nullptr);
    softmax_pack<<<8 * T_SEQ / 4, 256, 0, stream>>>(Sbuf);
    gemm83<0,0,true><<<dim3(1, T_SEQ/128, 16), 512, 0, stream>>>(
        (const f16*)Sbuf, (const f16*)Sbuf + T_SEQ, vh_g, vl_g, attn_g,
        T_SEQ, 2 * T_SEQ, T_SEQ, HID,
        (long)T_SEQ * 2 * T_SEQ, (long)HD * T_SEQ, 4, HD, nullptr);
  }

  // --- attn chunk-sum + hi/lo split, then fused 3-term wo projection (+resid)
  split_sum_k<<<(T_SEQ * HID) / (256 * 8), 256, 0, stream>>>(contrib, contrib + (size_t)T_SEQ * HID, ahh, ahl);
  gemm83<2,0,false><<<dim3(HID/128, T_SEQ/128, 1), 512, 0, stream>>>(
      ahh, ahl, woh, wol, h2, HID, HID, HID, HID, 0, 0, 0, 0, x);

  // --- norm2, gate (f32), routing (single-block build)
  rmsnorm_k<false><<<T_SEQ, 256, 0, stream>>>(h2, n2w, h2n, nullptr, invr2);
  gate_topk<<<T_SEQ, 256, 0, stream>>>(h2, invr2, n2w, gw, tidx, twt);
  route_build<<<1, 256, 0, stream>>>(tidx, goff, arows, crows);

  // --- MoE: fused w1+w3+silu -> gb, then w2 (split-K, weighted f16 stores)
  gemm_ffn<true><<<dim3(FFN_D/128, 16, NEXP), 256, 0, stream>>>(
      h2n, w1h, w3h, gb, HID, HID, HID, FFN_D, (long)FFN_D * HID, goff, arows);
  gemm8<false,true,4,1><<<dim3(HID/128, 16, 2 * NEXP), 256, 0, stream>>>(
      gb, w2h, contrib, contribH, FFN_D, FFN_D, FFN_D, HID, (long)HID * FFN_D,
      goff, nullptr, crows, twt);
  combine_k<<<(T_SEQ * HID) / (256 * 4), 256, 0, stream>>>(h2, (const f16*)contrib, contribH, out);
}

// Round 12
// 855.500 us; speedup vs baseline: 1.1669x; 1.0951x over previous
//
#include <hip/hip_runtime.h>
#include <math.h>

typedef __fp16 f16;
typedef __fp16 f16x8 __attribute__((ext_vector_type(8)));
typedef __fp16 f16x4 __attribute__((ext_vector_type(4)));
typedef float  f32x4 __attribute__((ext_vector_type(4)));

#define T_SEQ 2048
#define HID   2048
#define NQH   16
#define NKV   4
#define HD    128
#define FFN_D 4096
#define NEXP  8

// async global->LDS DMA, 16B per lane; LDS dest is wave-uniform base (+lane*16 in HW)
#define GLDS(gp, lp) __builtin_amdgcn_global_load_lds( \
    (const __attribute__((address_space(1))) void*)(gp), \
    (__attribute__((address_space(3))) void*)(lp), 16, 0, 0)

__device__ __forceinline__ float wredsum(float v){
#pragma unroll
  for (int m = 32; m; m >>= 1) v += __shfl_xor(v, m, 64);
  return v;
}
__device__ __forceinline__ float wredmax(float v){
#pragma unroll
  for (int m = 32; m; m >>= 1) v = fmaxf(v, __shfl_xor(v, m, 64));
  return v;
}

// ---------------------------------------------------------------------------
// Fused MoE FFN-up: G = silu(A*B1^T) * (A*B3^T), grouped per expert.
// B1/B3 read DIRECTLY as f32 (no conversion pass): staged f32 via gload_lds,
// converted to f16 fragments in-register ((f16) RNE cast == old conv kernel).
// 4-wave 128x128 (BK=32), 80KB LDS (A f16 | B1 f32 | B3 f32, 2 bufs), 2 blk/CU.
// Counted vmcnt(10) 2-deep. f32 row = 128B = 32 banks: granule swizzle
// g' = g ^ (row&7) on source AND read (rule #21) -> 2 lanes/bank-group (free).
// ---------------------------------------------------------------------------
template<bool GATHER_A>
__global__ __launch_bounds__(256, 2)
void gemm_ffn(const f16* __restrict__ A, const float* __restrict__ B1,
              const float* __restrict__ B3, f16* __restrict__ G,
              int K, int lda, int ldb, int ldg, long sBz,
              const int* __restrict__ grp_off, const int* __restrict__ a_rows)
{
  __shared__ __align__(16) f16 Lds[2][20480];  // A f16 @0 | B1 f32 @4096 | B3 f32 @12288 (f16 units)
  const int bn = blockIdx.x, bm = blockIdx.y, e = blockIdx.z;
  const int rowBase  = grp_off[e];
  const int rowCount = grp_off[e + 1] - rowBase;
  if (rowCount <= 0 || bm * 128 >= rowCount) return;
  const float* B1z = B1 + (long)e * sBz;
  const float* B3z = B3 + (long)e * sBz;
  const int nt = K >> 5;

  const int tid = threadIdx.x, lane = tid & 63, w = tid >> 6;
  const int wr = w >> 1, wc = w & 1;

  // A staging (f16): 2 sites x 64 rows; row = site*64 + tid>>2, src col swizzled
  const int sArow = tid >> 2;
  const int sAcol = (((tid & 3) ^ ((tid >> 3) & 3)) << 3);
  int aoff[2];
#pragma unroll
  for (int i = 0; i < 2; i++) {
    int r = bm * 128 + i * 64 + sArow;
    if (r > rowCount - 1) r = rowCount - 1;
    const int ar = GATHER_A ? a_rows[rowBase + r] : (rowBase + r);
    aoff[i] = ar * lda + sAcol;
  }
  // B staging (f32): 4 sites x 32 rows; row = site*32 + tid>>3, granule swizzled
  const int sBrow = tid >> 3;                      // 0..31
  const int sBcol = (((tid & 7) ^ ((tid >> 3) & 7)) << 2);  // f32 elems
  int boff[4];
#pragma unroll
  for (int i = 0; i < 4; i++)
    boff[i] = (bn * 128 + i * 32 + sBrow) * ldb + sBcol;

#define STGF(buf, kk) do { f16* _l = &Lds[buf][0]; \
  float* _b1 = (float*)(_l + 4096); float* _b3 = (float*)(_l + 12288); \
  GLDS(A   + aoff[0] + (kk), _l +        w * 512); \
  GLDS(A   + aoff[1] + (kk), _l + 2048 + w * 512); \
  GLDS(B1z + boff[0] + (kk), _b1 +        w * 256); \
  GLDS(B1z + boff[1] + (kk), _b1 + 1024 + w * 256); \
  GLDS(B1z + boff[2] + (kk), _b1 + 2048 + w * 256); \
  GLDS(B1z + boff[3] + (kk), _b1 + 3072 + w * 256); \
  GLDS(B3z + boff[0] + (kk), _b3 +        w * 256); \
  GLDS(B3z + boff[1] + (kk), _b3 + 1024 + w * 256); \
  GLDS(B3z + boff[2] + (kk), _b3 + 2048 + w * 256); \
  GLDS(B3z + boff[3] + (kk), _b3 + 3072 + w * 256); } while (0)

  const int fr = lane & 15, fq = lane >> 4;
  const int cpA  = ((fq ^ ((fr >> 1) & 3)) << 3);            // f16 elems
  const int aRow = (wr * 64 + fr) * 32;
  const int gB0  = (((2 * fq)     ^ (fr & 7)) << 2);         // f32 elems
  const int gB1  = (((2 * fq + 1) ^ (fr & 7)) << 2);
  const int bRowF = (wc * 64 + fr) * 32;                     // f32 row stride 32

  f32x4 acc1[4][4] = {};
  f32x4 acc3[4][4] = {};

  STGF(0, 0);
  if (nt > 1) STGF(1, 32);

  for (int kt = 0; kt < nt; kt++) {
    if (kt + 1 < nt) asm volatile("s_waitcnt vmcnt(10)" ::: "memory");
    else             asm volatile("s_waitcnt vmcnt(0)" ::: "memory");
    __builtin_amdgcn_s_barrier();
    const f16* Lb = &Lds[kt & 1][0];
    const float* B1b = (const float*)(Lb + 4096);
    const float* B3b = (const float*)(Lb + 12288);
    f16x8 af[4], b1f[4], b3f[4];
#pragma unroll
    for (int m = 0; m < 4; m++) af[m] = *(const f16x8*)(Lb + aRow + m * 512 + cpA);
#pragma unroll
    for (int n = 0; n < 4; n++) {
      const float4 u1 = *(const float4*)(B1b + bRowF + n * 512 + gB0);
      const float4 v1 = *(const float4*)(B1b + bRowF + n * 512 + gB1);
      const float4 u3 = *(const float4*)(B3b + bRowF + n * 512 + gB0);
      const float4 v3 = *(const float4*)(B3b + bRowF + n * 512 + gB1);
      b1f[n][0]=(f16)u1.x; b1f[n][1]=(f16)u1.y; b1f[n][2]=(f16)u1.z; b1f[n][3]=(f16)u1.w;
      b1f[n][4]=(f16)v1.x; b1f[n][5]=(f16)v1.y; b1f[n][6]=(f16)v1.z; b1f[n][7]=(f16)v1.w;
      b3f[n][0]=(f16)u3.x; b3f[n][1]=(f16)u3.y; b3f[n][2]=(f16)u3.z; b3f[n][3]=(f16)u3.w;
      b3f[n][4]=(f16)v3.x; b3f[n][5]=(f16)v3.y; b3f[n][6]=(f16)v3.z; b3f[n][7]=(f16)v3.w;
    }
    asm volatile("s_waitcnt lgkmcnt(0)" ::: "memory");
    __builtin_amdgcn_sched_barrier(0);
    __builtin_amdgcn_s_barrier();                 // all reads done -> safe to restage
    if (kt + 2 < nt) STGF(kt & 1, (kt + 2) * 32);
    __builtin_amdgcn_s_setprio(1);
#pragma unroll
    for (int m = 0; m < 4; m++)
#pragma unroll
      for (int n = 0; n < 4; n++) {
        acc1[m][n] = __builtin_amdgcn_mfma_f32_16x16x32_f16(af[m], b1f[n], acc1[m][n], 0, 0, 0);
        acc3[m][n] = __builtin_amdgcn_mfma_f32_16x16x32_f16(af[m], b3f[n], acc3[m][n], 0, 0, 0);
      }
    __builtin_amdgcn_s_setprio(0);
  }
#undef STGF

  const int ccol0 = bn * 128 + wc * 64 + fr;
#pragma unroll
  for (int m = 0; m < 4; m++) {
#pragma unroll
    for (int r = 0; r < 4; r++) {
      const int g = bm * 128 + wr * 64 + m * 16 + fq * 4 + r;
      if (g >= rowCount) continue;
      const long orow = rowBase + g;
#pragma unroll
      for (int n = 0; n < 4; n++) {
        const float h1 = acc1[m][n][r];
        const float h3 = acc3[m][n][r];
        const float s  = h1 / (1.0f + __expf(-h1));
        G[orow * ldg + (ccol0 + n * 16)] = (f16)(s * h3);
      }
    }
  }
}

// ---------------------------------------------------------------------------
// MoE down-proj (w2): 4-wave 128x128 (BK=32), B read directly as f32.
// LDS 48KB (A f16 | B f32, 2 bufs) -> 3 blocks/CU. Counted vmcnt(6) 2-deep.
// EPI=4: f16 store of tw[token,rank]*acc via scatter rows. MODE=1: split-K.
// ---------------------------------------------------------------------------
template<bool GATHER_A, bool SCATTER_C, int EPI, int MODE>
__global__ __launch_bounds__(256, 3)
void gemm8(const f16* __restrict__ A, const float* __restrict__ B,
           void* __restrict__ Cv, void* __restrict__ Cv2,
           int K, int lda, int ldb, int ldc, long sBz,
           const int* __restrict__ grp_off, const int* __restrict__ a_rows,
           const int* __restrict__ c_rows, const float* __restrict__ tw)
{
  __shared__ __align__(16) f16 Lds[2][12288];   // A f16 @0 (4096) | B f32 @4096 (16KB)
  const int bn = blockIdx.x, bm = blockIdx.y, z = blockIdx.z;
  int e = z, half = 0;
  if (MODE == 1) { e = z >> 1; half = z & 1; }
  const int rowBase  = grp_off[e];
  const int rowCount = grp_off[e + 1] - rowBase;
  if (rowCount <= 0 || bm * 128 >= rowCount) return;
  const float* Bz = B + (long)e * sBz;
  int k0 = 0, kN = K;
  if (MODE == 1) { kN = K >> 1; k0 = half * kN; }
  const int nt = kN >> 5;

  const int tid = threadIdx.x, lane = tid & 63, w = tid >> 6;
  const int wr = w >> 1, wc = w & 1;

  const int sArow = tid >> 2;
  const int sAcol = (((tid & 3) ^ ((tid >> 3) & 3)) << 3);
  int aoff[2];
#pragma unroll
  for (int i = 0; i < 2; i++) {
    int r = bm * 128 + i * 64 + sArow;
    if (r > rowCount - 1) r = rowCount - 1;
    const int ar = GATHER_A ? a_rows[rowBase + r] : (rowBase + r);
    aoff[i] = ar * lda + sAcol + k0;
  }
  const int sBrow = tid >> 3;
  const int sBcol = (((tid & 7) ^ ((tid >> 3) & 7)) << 2);
  int boff[4];
#pragma unroll
  for (int i = 0; i < 4; i++)
    boff[i] = (bn * 128 + i * 32 + sBrow) * ldb + sBcol + k0;

#define STG8(buf, kk) do { f16* _l = &Lds[buf][0]; \
  float* _b = (float*)(_l + 4096); \
  GLDS(A  + aoff[0] + (kk), _l +        w * 512); \
  GLDS(A  + aoff[1] + (kk), _l + 2048 + w * 512); \
  GLDS(Bz + boff[0] + (kk), _b +        w * 256); \
  GLDS(Bz + boff[1] + (kk), _b + 1024 + w * 256); \
  GLDS(Bz + boff[2] + (kk), _b + 2048 + w * 256); \
  GLDS(Bz + boff[3] + (kk), _b + 3072 + w * 256); } while (0)

  const int fr = lane & 15, fq = lane >> 4;
  const int cpA  = ((fq ^ ((fr >> 1) & 3)) << 3);
  const int aRow = (wr * 64 + fr) * 32;
  const int gB0  = (((2 * fq)     ^ (fr & 7)) << 2);
  const int gB1  = (((2 * fq + 1) ^ (fr & 7)) << 2);
  const int bRowF = (wc * 64 + fr) * 32;

  f32x4 acc[4][4] = {};

  STG8(0, 0);
  if (nt > 1) STG8(1, 32);

  for (int kt = 0; kt < nt; kt++) {
    if (kt + 1 < nt) asm volatile("s_waitcnt vmcnt(6)" ::: "memory");
    else             asm volatile("s_waitcnt vmcnt(0)" ::: "memory");
    __builtin_amdgcn_s_barrier();
    const f16* Lb = &Lds[kt & 1][0];
    const float* Bb = (const float*)(Lb + 4096);
    f16x8 af[4], bf[4];
#pragma unroll
    for (int m = 0; m < 4; m++) af[m] = *(const f16x8*)(Lb + aRow + m * 512 + cpA);
#pragma unroll
    for (int n = 0; n < 4; n++) {
      const float4 u = *(const float4*)(Bb + bRowF + n * 512 + gB0);
      const float4 v = *(const float4*)(Bb + bRowF + n * 512 + gB1);
      bf[n][0]=(f16)u.x; bf[n][1]=(f16)u.y; bf[n][2]=(f16)u.z; bf[n][3]=(f16)u.w;
      bf[n][4]=(f16)v.x; bf[n][5]=(f16)v.y; bf[n][6]=(f16)v.z; bf[n][7]=(f16)v.w;
    }
    asm volatile("s_waitcnt lgkmcnt(0)" ::: "memory");
    __builtin_amdgcn_sched_barrier(0);
    __builtin_amdgcn_s_barrier();                 // all reads of buf done -> safe to restage
    if (kt + 2 < nt) STG8(kt & 1, (kt + 2) * 32);
    __builtin_amdgcn_s_setprio(1);
#pragma unroll
    for (int m = 0; m < 4; m++)
#pragma unroll
      for (int n = 0; n < 4; n++)
        acc[m][n] = __builtin_amdgcn_mfma_f32_16x16x32_f16(af[m], bf[n], acc[m][n], 0, 0, 0);
    __builtin_amdgcn_s_setprio(0);
  }
#undef STG8

  float* Cf = (MODE == 1 && half) ? (float*)Cv2 : (float*)Cv;
  f16*   Ch = (MODE == 1 && half) ? (f16*)Cv2   : (f16*)Cv;
  const int ccol0 = bn * 128 + wc * 64 + fr;
#pragma unroll
  for (int m = 0; m < 4; m++) {
#pragma unroll
    for (int r = 0; r < 4; r++) {
      const int g = bm * 128 + wr * 64 + m * 16 + fq * 4 + r;
      if (g >= rowCount) continue;
      const long orow = SCATTER_C ? (long)c_rows[rowBase + g] : (long)(rowBase + g);
#pragma unroll
      for (int n = 0; n < 4; n++) {
        const long idx = orow * ldc + (ccol0 + n * 16);
        if (EPI == 4) {
          const int t = (int)(orow & (T_SEQ - 1)), kk = (int)(orow >> 11);
          Ch[idx] = (f16)(tw[t * 2 + kk] * acc[m][n][r]);
        }
        else if (EPI == 3) Ch[idx] = (f16)acc[m][n][r];
        else               Cf[idx] = acc[m][n][r];
      }
    }
  }
}

// ---------------------------------------------------------------------------
// 8-wave 128x128 (BK=64) fused hi/lo 3-term GEMM, counted 2-deep schedule:
//   C = Ah*Bh^T + Ah*Bl^T + Al*Bh^T   (fp32-faithful)
// IDENTITY block mapping. LDS 2 x 64KB (Ah|Al|Bh|Bl x 128x64).
// EPI: 0 f32, 2 f32+resid. CAUSAL: skip bn>bm.
// PVK: z = head | chunk<<3; K causally limited to (bm+1)*128; C += chunk*T*HID.
// ---------------------------------------------------------------------------
template<int EPI, int CAUSAL, bool PVK>
__global__ __launch_bounds__(512, 2)
void gemm83(const f16* __restrict__ Ah, const f16* __restrict__ Al,
            const f16* __restrict__ Bh, const f16* __restrict__ Bl,
            void* __restrict__ Cv, int K, int lda, int ldb, int ldc,
            long sAz, long sBz, int bdiv, long sCz,
            const float* __restrict__ resid)
{
  __shared__ __align__(16) f16 Lds[2][32768];  // Ah 0 | Al 8192 | Bh 16384 | Bl 24576
  const int bn = blockIdx.x, bm = blockIdx.y, z = blockIdx.z;
  if (CAUSAL == 1 && bn > bm) return;
  int head = z, chunk = 0;
  if (PVK) { head = z & 7; chunk = z >> 3; }
  int kstart = 0, kend = K;
  if (PVK) {
    const int km = (bm + 1) * 128;
    if (km < kend) kend = km;
    kstart = chunk * 1024;
    if (kstart >= kend) return;
    if (kend > kstart + 1024) kend = kstart + 1024;
  }
  const int nt = (kend - kstart) >> 6;

  const f16* Ahz = Ah + (long)head * sAz;
  const f16* Alz = Al + (long)head * sAz;
  const long zb = (long)(bdiv ? head / bdiv : head) * sBz;
  const f16* Bhz = Bh + zb;
  const f16* Blz = Bl + zb;

  const int tid = threadIdx.x, lane = tid & 63, w = tid >> 6;
  const int wr = w >> 2, wc = w & 3;

  const int srow = w * 8 + (lane >> 3);
  const int scol = (((lane & 7) ^ (lane >> 3)) << 3);
  long ar[2], br[2];
#pragma unroll
  for (int i = 0; i < 2; i++) {
    ar[i] = (long)(bm * 128 + i * 64 + srow) * lda + scol + kstart;
    br[i] = (long)(bn * 128 + i * 64 + srow) * ldb + scol + kstart;
  }

#define STG83(buf, kk) do { f16* _l = &Lds[buf][0]; \
  GLDS(Ahz + ar[0] + (kk), _l +         w * 512); GLDS(Ahz + ar[1] + (kk), _l +  4096 + w * 512); \
  GLDS(Alz + ar[0] + (kk), _l +  8192 + w * 512); GLDS(Alz + ar[1] + (kk), _l + 12288 + w * 512); \
  GLDS(Bhz + br[0] + (kk), _l + 16384 + w * 512); GLDS(Bhz + br[1] + (kk), _l + 20480 + w * 512); \
  GLDS(Blz + br[0] + (kk), _l + 24576 + w * 512); GLDS(Blz + br[1] + (kk), _l + 28672 + w * 512); } while (0)

  const int fr = lane & 15, fq = lane >> 4;
  const int cp0 = ((fq       ^ (fr & 7)) << 3);
  const int cp1 = (((4 | fq) ^ (fr & 7)) << 3);
  const int aRow = (wr * 64 + fr) * 64;           // + m*1024 ; Al at +8192
  const int bRow = 16384 + (wc * 32 + fr) * 64;   // + n*1024 ; Bl at +8192

  f32x4 acc[4][2] = {};

  STG83(0, 0);
  if (nt > 1) STG83(1, 64);

  for (int kt = 0; kt < nt; kt++) {
    if (kt + 1 < nt) asm volatile("s_waitcnt vmcnt(8)" ::: "memory");
    else             asm volatile("s_waitcnt vmcnt(0)" ::: "memory");
    __builtin_amdgcn_s_barrier();
    const f16* Lb = &Lds[kt & 1][0];
#pragma unroll
    for (int ks = 0; ks < 2; ks++) {
      const int cp = ks ? cp1 : cp0;
      f16x8 ah[4], al[4], bh[2], bl[2];
#pragma unroll
      for (int n = 0; n < 2; n++) {
        bh[n] = *(const f16x8*)(Lb + bRow +        n * 1024 + cp);
        bl[n] = *(const f16x8*)(Lb + bRow + 8192 + n * 1024 + cp);
      }
#pragma unroll
      for (int m = 0; m < 4; m++) {
        ah[m] = *(const f16x8*)(Lb + aRow +        m * 1024 + cp);
        al[m] = *(const f16x8*)(Lb + aRow + 8192 + m * 1024 + cp);
      }
      __builtin_amdgcn_s_setprio(1);
#pragma unroll
      for (int m = 0; m < 4; m++)
#pragma unroll
        for (int n = 0; n < 2; n++) {
          acc[m][n] = __builtin_amdgcn_mfma_f32_16x16x32_f16(ah[m], bh[n], acc[m][n], 0, 0, 0);
          acc[m][n] = __builtin_amdgcn_mfma_f32_16x16x32_f16(ah[m], bl[n], acc[m][n], 0, 0, 0);
          acc[m][n] = __builtin_amdgcn_mfma_f32_16x16x32_f16(al[m], bh[n], acc[m][n], 0, 0, 0);
        }
      __builtin_amdgcn_s_setprio(0);
    }
    __builtin_amdgcn_s_barrier();
    if (kt + 2 < nt) STG83(kt & 1, (kt + 2) * 64);
  }
#undef STG83

  float* Cf = (float*)Cv + (long)head * sCz + (PVK ? (long)chunk * T_SEQ * HID : 0);
  const int crow0 = bm * 128 + wr * 64 + fq * 4;
  const int ccol0 = bn * 128 + wc * 32 + fr;
#pragma unroll
  for (int m = 0; m < 4; m++) {
#pragma unroll
    for (int r = 0; r < 4; r++) {
      const long row = crow0 + m * 16 + r;
#pragma unroll
      for (int n = 0; n < 2; n++) {
        const long idx = row * ldc + (ccol0 + n * 16);
        const float v = acc[m][n][r];
        if (EPI == 2) Cf[idx] = v + resid[idx];
        else          Cf[idx] = v;
      }
    }
  }
}

// ---------------------------------------------------------------------------
template<bool SPLIT>
__global__ __launch_bounds__(256)
void rmsnorm_k(const float* __restrict__ x, const float* __restrict__ w,
               f16* __restrict__ hi, f16* __restrict__ lo, float* __restrict__ invr_out)
{
  const int t = blockIdx.x, tid = threadIdx.x;
  const float4* xr = (const float4*)(x + (long)t * HID);
  const float4 a = xr[tid * 2], b = xr[tid * 2 + 1];
  float ss = a.x*a.x + a.y*a.y + a.z*a.z + a.w*a.w
           + b.x*b.x + b.y*b.y + b.z*b.z + b.w*b.w;
  ss = wredsum(ss);
  __shared__ float red[4];
  if ((tid & 63) == 0) red[tid >> 6] = ss;
  __syncthreads();
  const float tot  = red[0] + red[1] + red[2] + red[3];
  const float invr = 1.0f / sqrtf(tot * (1.0f / HID) + 1e-5f);
  if (invr_out && tid == 0) invr_out[t] = invr;
  const float4* wr4 = (const float4*)w;
  const float4 wa = wr4[tid * 2], wb = wr4[tid * 2 + 1];
  const float vals[8] = { a.x*wa.x, a.y*wa.y, a.z*wa.z, a.w*wa.w,
                          b.x*wb.x, b.y*wb.y, b.z*wb.z, b.w*wb.w };
  f16x8 hv, lv;
#pragma unroll
  for (int j = 0; j < 8; j++) {
    const float y = vals[j] * invr;
    const f16 h = (f16)y;
    hv[j] = h;
    if (SPLIT) lv[j] = (f16)(y - (float)h);
  }
  const long base = (long)t * HID + tid * 8;
  *(f16x8*)(hi + base) = hv;
  if (SPLIT) *(f16x8*)(lo + base) = lv;
}

// RoPE + hi/lo split; q -> (h,T,128), k -> (g,T,128), v -> transposed (g,128,T)
__global__ __launch_bounds__(256)
void rope_split_k(const float* __restrict__ qkv, const int* __restrict__ pos,
                  f16* __restrict__ qh, f16* __restrict__ ql,
                  f16* __restrict__ kh, f16* __restrict__ kl,
                  f16* __restrict__ vh, f16* __restrict__ vl)
{
  const int t = blockIdx.x, tid = threadIdx.x;
  __shared__ float invf[64];
  if (tid < 64) {
    const float y = (float)tid * (1.0f / 64.0f);
    invf[tid] = 1.0f / (float)pow(10000.0, (double)y);   // f32-rounded exact pow
  }
  __syncthreads();
  const float p = (float)pos[t];
  const float* row = qkv + (long)t * 3072;

#pragma unroll
  for (int i = 0; i < 4; i++) {
    const int pi = tid + i * 256;
    const int h = pi >> 6, d = pi & 63;
    const float ang = p * invf[d];
    float s, c; sincosf(ang, &s, &c);
    const float x1 = row[h * 128 + d], x2 = row[h * 128 + 64 + d];
    const float o1 = x1 * c - x2 * s;
    const float o2 = x2 * c + x1 * s;
    const long base = ((long)h * T_SEQ + t) * HD;
    { const f16 hh = (f16)o1; qh[base + d]      = hh; ql[base + d]      = (f16)(o1 - (float)hh); }
    { const f16 hh = (f16)o2; qh[base + 64 + d] = hh; ql[base + 64 + d] = (f16)(o2 - (float)hh); }
  }
  {
    const int g = tid >> 6, d = tid & 63;
    const float ang = p * invf[d];
    float s, c; sincosf(ang, &s, &c);
    const float x1 = row[2048 + g * 128 + d], x2 = row[2048 + g * 128 + 64 + d];
    const float o1 = x1 * c - x2 * s;
    const float o2 = x2 * c + x1 * s;
    const long base = ((long)g * T_SEQ + t) * HD;
    { const f16 hh = (f16)o1; kh[base + d]      = hh; kl[base + d]      = (f16)(o1 - (float)hh); }
    { const f16 hh = (f16)o2; kh[base + 64 + d] = hh; kl[base + 64 + d] = (f16)(o2 - (float)hh); }
  }
#pragma unroll
  for (int i = 0; i < 2; i++) {
    const int e = tid + i * 256;
    const int g = e >> 7, d = e & 127;
    const float v = row[2560 + e];
    const long idx = ((long)g * HD + d) * T_SEQ + t;
    const f16 h = (f16)v; vh[idx] = h; vl[idx] = (f16)(v - (float)h);
  }
}

// Row softmax over f32 scores, causal mask, pack P as [hi f16 x 2048 | lo f16 x 2048]
// in place. Causal-bounded: row t touches only segments < (t>>8)+1.
__global__ __launch_bounds__(256)
void softmax_pack(float* __restrict__ S)
{
  const int row  = blockIdx.x * 4 + (threadIdx.x >> 6);
  const int lane = threadIdx.x & 63;
  const int t    = row & (T_SEQ - 1);
  const int nseg = (t >> 8) + 1;
  float* Sr = S + (long)row * T_SEQ;
  float4 v[8];
  const float4* Sr4 = (const float4*)Sr;
#pragma unroll
  for (int i = 0; i < 8; i++) if (i < nseg) v[i] = Sr4[i * 64 + lane];
  const float scale = 0.08838834764831843f; // 128^-0.5
  float vmax = -3.4e38f;
#pragma unroll
  for (int i = 0; i < 8; i++) {
    if (i >= nseg) continue;
    float* pv = (float*)&v[i];
    const int s0 = (i * 64 + lane) * 4;
#pragma unroll
    for (int j = 0; j < 4; j++) {
      const float xx = (s0 + j <= t) ? pv[j] * scale : -3.4e38f;
      pv[j] = xx;
      vmax = fmaxf(vmax, xx);
    }
  }
  vmax = wredmax(vmax);
  float sum = 0.f;
#pragma unroll
  for (int i = 0; i < 8; i++) {
    if (i >= nseg) continue;
    float* pv = (float*)&v[i];
#pragma unroll
    for (int j = 0; j < 4; j++) {
      const float e = (pv[j] > -3.0e38f) ? __expf(pv[j] - vmax) : 0.f;
      pv[j] = e; sum += e;
    }
  }
  sum = wredsum(sum);
  const float rinv = 1.0f / sum;
  __syncthreads();
  f16* P = (f16*)Sr;
#pragma unroll
  for (int i = 0; i < 8; i++) {
    if (i >= nseg) continue;
    const int s0 = (i * 64 + lane) * 4;
    float* pv = (float*)&v[i];
    f16x4 hv, lv;
#pragma unroll
    for (int j = 0; j < 4; j++) {
      const float pr = pv[j] * rinv;
      const f16 ph = (f16)pr;
      hv[j] = ph; lv[j] = (f16)(pr - (float)ph);
    }
    *(f16x4*)(P + s0)         = hv;
    *(f16x4*)(P + T_SEQ + s0) = lv;
  }
}

// Gate: f32 logits from f32 h2 (re-normalized), top-2 + renormalized weights.
__global__ __launch_bounds__(256)
void gate_topk(const float* __restrict__ h2, const float* __restrict__ invr,
               const float* __restrict__ n2w, const float* __restrict__ gw,
               int* __restrict__ top_idx, float* __restrict__ top_w)
{
  const int t = blockIdx.x, tid = threadIdx.x;
  const float r = invr[t];
  const float4* xr = (const float4*)(h2 + (long)t * HID);
  const float4 a = xr[tid * 2], b = xr[tid * 2 + 1];
  const float4* wr4 = (const float4*)n2w;
  const float4 wa = wr4[tid * 2], wb = wr4[tid * 2 + 1];
  const float hn[8] = { a.x*wa.x*r, a.y*wa.y*r, a.z*wa.z*r, a.w*wa.w*r,
                        b.x*wb.x*r, b.y*wb.y*r, b.z*wb.z*r, b.w*wb.w*r };
  float part[8];
#pragma unroll
  for (int e = 0; e < 8; e++) {
    const float4* g4 = (const float4*)(gw + (long)e * HID + tid * 8);
    const float4 ga = g4[0], gb = g4[1];
    part[e] = hn[0]*ga.x + hn[1]*ga.y + hn[2]*ga.z + hn[3]*ga.w
            + hn[4]*gb.x + hn[5]*gb.y + hn[6]*gb.z + hn[7]*gb.w;
  }
#pragma unroll
  for (int e = 0; e < 8; e++) part[e] = wredsum(part[e]);
  __shared__ float red[4][8];
  if ((tid & 63) == 0) {
#pragma unroll
    for (int e = 0; e < 8; e++) red[tid >> 6][e] = part[e];
  }
  __syncthreads();
  if (tid == 0) {
    float lg[8];
#pragma unroll
    for (int e = 0; e < 8; e++) lg[e] = red[0][e] + red[1][e] + red[2][e] + red[3][e];
    int i1 = 0;
    for (int e = 1; e < 8; e++) if (lg[e] > lg[i1]) i1 = e;
    int i2 = -1;
    for (int e = 0; e < 8; e++) { if (e == i1) continue; if (i2 < 0 || lg[e] > lg[i2]) i2 = e; }
    const float q = expf(lg[i2] - lg[i1]);
    top_idx[t * 2] = i1; top_idx[t * 2 + 1] = i2;
    top_w[t * 2]     = 1.0f / (1.0f + q);
    top_w[t * 2 + 1] = q / (1.0f + q);
  }
}

// Single-block routing build: count -> scan -> fill.
__global__ __launch_bounds__(256)
void route_build(const int* __restrict__ ti, int* __restrict__ goff,
                 int* __restrict__ arows, int* __restrict__ crows)
{
  __shared__ int cnt[8], cur[8], off[9];
  const int tid = threadIdx.x;
  if (tid < 8) { cnt[tid] = 0; cur[tid] = 0; }
  __syncthreads();
  for (int i = tid; i < 2 * T_SEQ; i += 256) atomicAdd(&cnt[ti[i]], 1);
  __syncthreads();
  if (tid == 0) {
    int s = 0;
    for (int e = 0; e < NEXP; e++) { off[e] = s; s += cnt[e]; }
    off[NEXP] = s;
    for (int e = 0; e <= NEXP; e++) goff[e] = off[e];
  }
  __syncthreads();
  for (int i = tid; i < 2 * T_SEQ; i += 256) {
    const int e = ti[i];
    const int p = atomicAdd(&cur[e], 1);
    const int slot = off[e] + p;
    arows[slot] = i >> 1;
    crows[slot] = (i & 1) * T_SEQ + (i >> 1);
  }
}

__global__ __launch_bounds__(256)
void split_pair_k(const float* __restrict__ src, f16* __restrict__ hi, f16* __restrict__ lo)
{
  const long i = ((long)blockIdx.x * 256 + threadIdx.x) * 8;
  const float4 a = *(const float4*)(src + i);
  const float4 b = *(const float4*)(src + i + 4);
  const float vals[8] = {a.x,a.y,a.z,a.w,b.x,b.y,b.z,b.w};
  f16x8 hv, lv;
#pragma unroll
  for (int j = 0; j < 8; j++) { const f16 h = (f16)vals[j]; hv[j] = h; lv[j] = (f16)(vals[j] - (float)h); }
  *(f16x8*)(hi + i) = hv;
  *(f16x8*)(lo + i) = lv;
}

// attn = chunk0 + (t>=1024 ? chunk1 : 0), then hi/lo split
__global__ __launch_bounds__(256)
void split_sum_k(const float* __restrict__ c0, const float* __restrict__ c1,
                 f16* __restrict__ hi, f16* __restrict__ lo)
{
  const long i = ((long)blockIdx.x * 256 + threadIdx.x) * 8;
  const int t = (int)(i >> 11);
  const float4 a = *(const float4*)(c0 + i);
  const float4 b = *(const float4*)(c0 + i + 4);
  float4 ca = {0,0,0,0}, cb = {0,0,0,0};
  if (t >= 1024) { ca = *(const float4*)(c1 + i); cb = *(const float4*)(c1 + i + 4); }
  const float vals[8] = {a.x+ca.x, a.y+ca.y, a.z+ca.z, a.w+ca.w,
                         b.x+cb.x, b.y+cb.y, b.z+cb.z, b.w+cb.w};
  f16x8 hv, lv;
#pragma unroll
  for (int j = 0; j < 8; j++) { const f16 h = (f16)vals[j]; hv[j] = h; lv[j] = (f16)(vals[j] - (float)h); }
  *(f16x8*)(hi + i) = hv;
  *(f16x8*)(lo + i) = lv;
}

// out = h2 + c0[kk=0] + c1[kk=0] + c0[kk=1] + c1[kk=1]   (f16 contribs, pre-weighted)
__global__ __launch_bounds__(256)
void combine_k(const float* __restrict__ h2, const f16* __restrict__ c0,
               const f16* __restrict__ c1, float* __restrict__ out)
{
  const long i = ((long)blockIdx.x * 256 + threadIdx.x) * 4;
  const float4 a = *(const float4*)(h2 + i);
  const f16x4 p0 = *(const f16x4*)(c0 + i);
  const f16x4 p1 = *(const f16x4*)(c1 + i);
  const f16x4 q0 = *(const f16x4*)(c0 + (long)T_SEQ * HID + i);
  const f16x4 q1 = *(const f16x4*)(c1 + (long)T_SEQ * HID + i);
  float4 o;
  o.x = a.x + (float)p0[0] + (float)p1[0] + (float)q0[0] + (float)q1[0];
  o.y = a.y + (float)p0[1] + (float)p1[1] + (float)q0[1] + (float)q1[1];
  o.z = a.z + (float)p0[2] + (float)p1[2] + (float)q0[2] + (float)q1[2];
  o.w = a.w + (float)p0[3] + (float)p1[3] + (float)q0[3] + (float)q1[3];
  *(float4*)(out + i) = o;
}

// ---------------------------------------------------------------------------
extern "C" void kernel_launch(void* const* d_in, const int* in_sizes, int n_in,
                              void* d_out, int out_size, void* d_ws, size_t ws_size,
                              hipStream_t stream)
{
  const float* x    = (const float*)d_in[0];
  const int*   pos  = (const int*)d_in[1];
  const float* n1w  = (const float*)d_in[2];
  const float* n2w  = (const float*)d_in[3];
  const float* wqkv = (const float*)d_in[4];
  const float* wo   = (const float*)d_in[5];
  const float* gw   = (const float*)d_in[6];
  const float* w1   = (const float*)d_in[7];
  const float* w2   = (const float*)d_in[8];
  const float* w3   = (const float*)d_in[9];
  float* out = (float*)d_out;

  char* base = (char*)d_ws;
  size_t off = 0;
  auto alloc = [&](size_t bytes) -> char* {
    char* r = base + off;
    off += (bytes + 255) & ~(size_t)255;
    return r;
  };
  f16* wqh = (f16*)alloc((size_t)3072 * HID * 2);
  f16* wql = (f16*)alloc((size_t)3072 * HID * 2);
  f16* woh = (f16*)alloc((size_t)HID * HID * 2);
  f16* wol = (f16*)alloc((size_t)HID * HID * 2);
  f16* qh  = (f16*)alloc((size_t)NQH * T_SEQ * HD * 2);
  f16* ql  = (f16*)alloc((size_t)NQH * T_SEQ * HD * 2);
  f16* kh  = (f16*)alloc((size_t)NKV * T_SEQ * HD * 2);
  f16* kl  = (f16*)alloc((size_t)NKV * T_SEQ * HD * 2);
  f16* vh  = (f16*)alloc((size_t)NKV * T_SEQ * HD * 2);
  f16* vl  = (f16*)alloc((size_t)NKV * T_SEQ * HD * 2);
  float* h2      = (float*)alloc((size_t)T_SEQ * HID * 4);
  f16*   h2n     = (f16*)alloc((size_t)T_SEQ * HID * 2);
  float* contrib = (float*)alloc((size_t)2 * T_SEQ * HID * 4); // PV out (2 chunks) -> MoE contrib (f16) half0
  float* invr2 = (float*)alloc(T_SEQ * 4);
  int*   tidx  = (int*)alloc(T_SEQ * 2 * 4);
  float* twt   = (float*)alloc(T_SEQ * 2 * 4);
  int*   goff   = (int*)alloc(256);   // [0..8]
  int*   arows  = (int*)alloc(2 * T_SEQ * 4);
  int*   crows  = (int*)alloc(2 * T_SEQ * 4);
  // unions (lifetime-disjoint)
  char* uA = alloc((size_t)T_SEQ * 3072 * 4);      // qkv f32
  float* qkvf = (float*)uA;
  char* uB = alloc((size_t)T_SEQ * HID * 2);       // h hi -> attn hi
  f16* hh = (f16*)uB; f16* ahh = (f16*)uB;
  char* uC = alloc((size_t)T_SEQ * HID * 2);       // h lo -> attn lo
  f16* hl = (f16*)uC; f16* ahl = (f16*)uC;
  char* uS = alloc((size_t)8 * T_SEQ * T_SEQ * 4); // S (8 heads) -> gb + contribH
  float* Sbuf = (float*)uS;
  f16* gb  = (f16*)(uS + (size_t)4 * T_SEQ * FFN_D * 2);
  f16* contribH = (f16*)(uS + (size_t)6 * T_SEQ * FFN_D * 2);

  if (off > ws_size) return;

  // --- small weight conversions (QKV/wo only; MoE weights read as f32 in-GEMM)
  split_pair_k<<<(3072 * HID) / (256 * 8), 256, 0, stream>>>(wqkv, wqh, wql);
  split_pair_k<<<(HID * HID) / (256 * 8), 256, 0, stream>>>(wo, woh, wol);

  // --- norm1 + fused 3-term QKV
  rmsnorm_k<true><<<T_SEQ, 256, 0, stream>>>(x, n1w, hh, hl, nullptr);
  gemm83<0,0,false><<<dim3(3072/128, T_SEQ/128, 1), 512, 0, stream>>>(
      hh, hl, wqh, wql, qkvf, HID, HID, HID, 3072, 0, 0, 0, 0, nullptr);
  rope_split_k<<<T_SEQ, 256, 0, stream>>>(qkvf, pos, qh, ql, kh, kl, vh, vl);

  // --- attention, two groups of 8 heads (S buffer reused)
  for (int grp = 0; grp < 2; grp++) {
    const f16* qh_g = qh + (size_t)grp * 8 * T_SEQ * HD;
    const f16* ql_g = ql + (size_t)grp * 8 * T_SEQ * HD;
    const f16* kh_g = kh + (size_t)grp * 2 * T_SEQ * HD;
    const f16* kl_g = kl + (size_t)grp * 2 * T_SEQ * HD;
    const f16* vh_g = vh + (size_t)grp * 2 * HD * T_SEQ;
    const f16* vl_g = vl + (size_t)grp * 2 * HD * T_SEQ;
    float* attn_g = contrib + (size_t)grp * 8 * HD;   // column offset within [T][2048]
    gemm83<0,1,false><<<dim3(T_SEQ/128, T_SEQ/128, 8), 512, 0, stream>>>(
        qh_g, ql_g, kh_g, kl_g, Sbuf, HD, HD, HD, T_SEQ,
        (long)T_SEQ * HD, (long)T_SEQ * HD, 4, (long)T_SEQ * T_SEQ, nullptr);
    softmax_pack<<<8 * T_SEQ / 4, 256, 0, stream>>>(Sbuf);
    gemm83<0,0,true><<<dim3(1, T_SEQ/128, 16), 512, 0, stream>>>(
        (const f16*)Sbuf, (const f16*)Sbuf + T_SEQ, vh_g, vl_g, attn_g,
        T_SEQ, 2 * T_SEQ, T_SEQ, HID,
        (long)T_SEQ * 2 * T_SEQ, (long)HD * T_SEQ, 4, HD, nullptr);
  }

  // --- attn chunk-sum + hi/lo split, then fused 3-term wo projection (+resid)
  split_sum_k<<<(T_SEQ * HID) / (256 * 8), 256, 0, stream>>>(contrib, contrib + (size_t)T_SEQ * HID, ahh, ahl);
  gemm83<2,0,false><<<dim3(HID/128, T_SEQ/128, 1), 512, 0, stream>>>(
      ahh, ahl, woh, wol, h2, HID, HID, HID, HID, 0, 0, 0, 0, x);

  // --- norm2, gate (f32), routing (single-block build)
  rmsnorm_k<false><<<T_SEQ, 256, 0, stream>>>(h2, n2w, h2n, nullptr, invr2);
  gate_topk<<<T_SEQ, 256, 0, stream>>>(h2, invr2, n2w, gw, tidx, twt);
  route_build<<<1, 256, 0, stream>>>(tidx, goff, arows, crows);

  // --- MoE: fused w1+w3+silu -> gb (f32 weights direct), then w2 (f32 direct,
  //     split-K, routing-weighted f16 stores)
  gemm_ffn<true><<<dim3(FFN_D/128, 16, NEXP), 256, 0, stream>>>(
      h2n, w1, w3, gb, HID, HID, HID, FFN_D, (long)FFN_D * HID, goff, arows);
  gemm8<false,true,4,1><<<dim3(HID/128, 16, 2 * NEXP), 256, 0, stream>>>(
      gb, w2, contrib, contribH, FFN_D, FFN_D, FFN_D, HID, (long)HID * FFN_D,
      goff, nullptr, crows, twt);
  combine_k<<<(T_SEQ * HID) / (256 * 4), 256, 0, stream>>>(h2, (const f16*)contrib, contribH, out);
}